// Round 7
// baseline (2723.140 us; speedup 1.0000x reference)
//
#include <hip/hip_runtime.h>

#define N_NODES 30000
#define N_EDGES 240000
#define NF 32
#define EF 16
#define HF 64
#define NC 8

#define EB_GRID  938   // (N_EDGES + 255) / 256
#define NB2_GRID 235   // (2*N_NODES + 255) / 256
#define ZSTR     17    // sZ row stride (odd -> free 2-way bank aliasing)
#define NBLK_P   1024  // persistent grid: 4 blocks/CU x 256 CUs (guaranteed resident)
#define NROLES   (NB2_GRID + EB_GRID)   // 1173

// wbuf layout (float offsets)
#define W_COMB 0
#define B_COMB 256
#define W_NC   272
#define B_VEC  784
#define W_SD   816
#define W_NB   1840
#define B_SD   2864
#define B_NB   2896
#define W_NF   2928
#define B_NF   3184

// precompute LDS staging layout (float offsets)
#define LWn   0
#define LWe   2048
#define LWem  3072
#define LWnm  6144
#define LWfc  10240
#define Lbn   10752
#define Lbe   10816
#define Lbem  10880
#define Lbnm  10896
#define Lbfc  10928
#define LTOT  10936

__device__ __forceinline__ float sigmoidf_(float x) {
  return 1.0f / (1.0f + __expf(-x));
}

// ---------------------------------------------------------------------------
// software global barrier: monotonic-phase sense. Requires all NBLK_P blocks
// resident (guaranteed: launch_bounds(256,4) & LDS 30.2KB -> capacity 1024).
// __syncthreads drains each wave's stores to L2; agent-scope ACQ_REL atomics
// write back / invalidate L2 across XCDs.
// ---------------------------------------------------------------------------
__device__ __forceinline__ void gbarrier(int* bar, int phase) {
  __syncthreads();
  if (threadIdx.x == 0) {
    int prev = __hip_atomic_fetch_add(&bar[0], 1, __ATOMIC_ACQ_REL,
                                      __HIP_MEMORY_SCOPE_AGENT);
    if (prev == NBLK_P - 1) {
      __hip_atomic_store(&bar[0], 0, __ATOMIC_RELAXED, __HIP_MEMORY_SCOPE_AGENT);
      __hip_atomic_store(&bar[1], phase, __ATOMIC_RELEASE, __HIP_MEMORY_SCOPE_AGENT);
    } else {
      int v;
      do {
        __builtin_amdgcn_s_sleep(2);
        v = __hip_atomic_load(&bar[1], __ATOMIC_ACQUIRE, __HIP_MEMORY_SCOPE_AGENT);
      } while (v < phase);
    }
  }
  __syncthreads();
}

// ---------------------------------------------------------------------------
// hist (blocks 0..EB-1) + precompute (block EB) — LDS-staged weight folding.
// Block EB thread 0 also zeroes the barrier state (re-zeroed every replay).
// ---------------------------------------------------------------------------
__global__ void __launch_bounds__(256) hist_pre_kernel(
    const int* __restrict__ dst, int* __restrict__ cnt,
    const float* __restrict__ Wn, const float* __restrict__ bn,
    const float* __restrict__ We, const float* __restrict__ be,
    const float* __restrict__ Wem, const float* __restrict__ bem,
    const float* __restrict__ Wnm, const float* __restrict__ bnm,
    const float* __restrict__ Wfc, const float* __restrict__ bfc,
    float* __restrict__ wbuf, int* __restrict__ bar) {
  __shared__ float sW[LTOT];
  if (blockIdx.x < EB_GRID) {
    int e = blockIdx.x * 256 + threadIdx.x;
    if (e < N_EDGES) atomicAdd(&cnt[dst[e]], 1);
    return;
  }
  int tid = threadIdx.x;
  if (tid == 0) { bar[0] = 0; bar[1] = 0; }
  for (int i = tid; i < 2048; i += 256) sW[LWn + i] = Wn[i];
  for (int i = tid; i < 1024; i += 256) sW[LWe + i] = We[i];
  for (int i = tid; i < 3072; i += 256) sW[LWem + i] = Wem[i];
  for (int i = tid; i < 4096; i += 256) sW[LWnm + i] = Wnm[i];
  for (int i = tid; i < 512; i += 256) sW[LWfc + i] = Wfc[i];
  if (tid < 64) sW[Lbn + tid] = bn[tid];
  if (tid < 64) sW[Lbe + tid] = be[tid];
  if (tid < 16) sW[Lbem + tid] = bem[tid];
  if (tid < 32) sW[Lbnm + tid] = bnm[tid];
  if (tid < 8)  sW[Lbfc + tid] = bfc[tid];
  __syncthreads();
  {  // Wcomb
    int r = tid >> 4, c = tid & 15;
    float acc = 0.f;
    for (int j = 0; j < HF; ++j)
      acc = fmaf(sW[LWe + r * HF + j], sW[LWem + (HF + j) * EF + c], acc);
    wbuf[W_COMB + tid] = acc;
  }
  for (int idx = tid; idx < EF * NF; idx += 256) {  // Wnc
    int r = idx >> 5, c = idx & 31;
    float acc = 0.f;
    for (int j = 0; j < HF; ++j)
      acc = fmaf(sW[LWe + r * HF + j], sW[LWnm + j * NF + c], acc);
    wbuf[W_NC + idx] = acc;
  }
  for (int idx = tid; idx < NF * NF; idx += 256) {  // WSD
    int r = idx >> 5, c = idx & 31;
    float acc = 0.f;
    if (c < EF) {
      for (int j = 0; j < HF; ++j)
        acc = fmaf(sW[LWn + r * HF + j], sW[LWem + j * EF + c], acc);
    } else {
      int cc = c - EF;
      for (int j = 0; j < HF; ++j)
        acc = fmaf(sW[LWn + r * HF + j], sW[LWem + (2 * HF + j) * EF + cc], acc);
    }
    wbuf[W_SD + idx] = acc;
  }
  for (int idx = tid; idx < NF * NF; idx += 256) {  // WnB
    int r = idx >> 5, c = idx & 31;
    float acc = 0.f;
    for (int j = 0; j < HF; ++j)
      acc = fmaf(sW[LWn + r * HF + j], sW[LWnm + (HF + j) * NF + c], acc);
    wbuf[W_NB + idx] = acc;
  }
  if (tid < NF * NC) {  // Wnf
    int r = tid >> 3, c = tid & 7;
    float acc = 0.f;
    for (int j = 0; j < HF; ++j)
      acc = fmaf(sW[LWn + r * HF + j], sW[LWfc + j * NC + c], acc);
    wbuf[W_NF + tid] = acc;
  }
  if (tid < EF) {  // bcomb
    float acc = sW[Lbem + tid];
    for (int j = 0; j < HF; ++j)
      acc = fmaf(sW[Lbe + j], sW[LWem + (HF + j) * EF + tid], acc);
    wbuf[B_COMB + tid] = acc;
  }
  if (tid < NF) {  // bvec
    float acc = 0.f;
    for (int j = 0; j < HF; ++j)
      acc = fmaf(sW[Lbe + j], sW[LWnm + j * NF + tid], acc);
    wbuf[B_VEC + tid] = acc;
  }
  if (tid < NF) {  // bSD
    float acc = 0.f;
    if (tid < EF) {
      for (int j = 0; j < HF; ++j)
        acc = fmaf(sW[Lbn + j], sW[LWem + j * EF + tid], acc);
    } else {
      int cc = tid - EF;
      for (int j = 0; j < HF; ++j)
        acc = fmaf(sW[Lbn + j], sW[LWem + (2 * HF + j) * EF + cc], acc);
    }
    wbuf[B_SD + tid] = acc;
  }
  if (tid < NF) {  // bNB
    float acc = sW[Lbnm + tid];
    for (int j = 0; j < HF; ++j)
      acc = fmaf(sW[Lbn + j], sW[LWnm + (HF + j) * NF + tid], acc);
    wbuf[B_NB + tid] = acc;
  }
  if (tid < NC) {  // bnf
    float acc = sW[Lbfc + tid];
    for (int j = 0; j < HF; ++j)
      acc = fmaf(sW[Lbn + j], sW[LWfc + j * NC + tid], acc);
    wbuf[B_NF + tid] = acc;
  }
}

// exclusive scan of cnt[30000] -> off[30001], cursor = copy of off
__global__ void __launch_bounds__(1024) scan_kernel(
    const int* __restrict__ cnt, int* __restrict__ off, int* __restrict__ cursor) {
  __shared__ int part[1024];
  int t = threadIdx.x;
  const int CH = (N_NODES + 1023) / 1024;   // 30
  int base = t * CH;
  int lc[CH];
  int sum = 0;
  for (int i = 0; i < CH; ++i) {
    int idx = base + i;
    lc[i] = (idx < N_NODES) ? cnt[idx] : 0;
    sum += lc[i];
  }
  part[t] = sum;
  __syncthreads();
  for (int ofs = 1; ofs < 1024; ofs <<= 1) {
    int v = (t >= ofs) ? part[t - ofs] : 0;
    __syncthreads();
    part[t] += v;
    __syncthreads();
  }
  int run = (t == 0) ? 0 : part[t - 1];
  for (int i = 0; i < CH; ++i) {
    int idx = base + i;
    if (idx < N_NODES) {
      off[idx] = run;
      cursor[idx] = run;
      run += lc[i];
    }
  }
  if (t == 1023) off[N_NODES] = part[1023];
}

// ---------------------------------------------------------------------------
// scatter (blocks 0..EB-1) + init_proj (blocks EB..EB+NB2-1).
// ---------------------------------------------------------------------------
__global__ void __launch_bounds__(256) scatter_init_kernel(
    const float* __restrict__ edge_feat, const int* __restrict__ src,
    const int* __restrict__ dst, int* __restrict__ cursor,
    unsigned short* __restrict__ src_s, unsigned short* __restrict__ dst_s,
    float* __restrict__ e_buf,
    const float* __restrict__ node_feat, const float* __restrict__ wbuf,
    float* __restrict__ Ps, float* __restrict__ Pd, float* __restrict__ hpart) {
  if (blockIdx.x < EB_GRID) {
    int e = blockIdx.x * 256 + threadIdx.x;
    if (e >= N_EDGES) return;
    int d = dst[e];
    int pos = atomicAdd(&cursor[d], 1);
    src_s[pos] = (unsigned short)src[e];
    dst_s[pos] = (unsigned short)d;
    const float4* ep = (const float4*)(edge_feat + (size_t)e * EF);
    float4* op = (float4*)(e_buf + (size_t)pos * EF);
    op[0] = ep[0]; op[1] = ep[1]; op[2] = ep[2]; op[3] = ep[3];
    return;
  }
  __shared__ float sPRJ[2048];
  __shared__ float sPB[64];
  for (int i = threadIdx.x; i < 2048; i += 256) sPRJ[i] = wbuf[W_SD + i];
  if (threadIdx.x < 64) sPB[threadIdx.x] = wbuf[B_SD + threadIdx.x];
  __syncthreads();
  int gid = (blockIdx.x - EB_GRID) * 256 + threadIdx.x;
  int n = gid >> 1, p = gid & 1;
  if (n >= N_NODES) return;
  float x[NF];
  const float4* xp = (const float4*)(node_feat + (size_t)n * NF);
#pragma unroll
  for (int k4 = 0; k4 < 8; ++k4) {
    float4 v = xp[k4];
    x[4 * k4] = v.x; x[4 * k4 + 1] = v.y; x[4 * k4 + 2] = v.z; x[4 * k4 + 3] = v.w;
  }
  float pr[NF];
  const float* pb = sPB + p * 32;
#pragma unroll
  for (int j = 0; j < NF; ++j) pr[j] = pb[j];
  const float* wbase = sPRJ + p * 1024;
  for (int k = 0; k < NF; ++k) {
    float v = x[k];
    const float4* wr = (const float4*)(wbase + k * NF);
#pragma unroll
    for (int j4 = 0; j4 < 8; ++j4) {
      float4 w = wr[j4];
      pr[4 * j4 + 0] = fmaf(v, w.x, pr[4 * j4 + 0]);
      pr[4 * j4 + 1] = fmaf(v, w.y, pr[4 * j4 + 1]);
      pr[4 * j4 + 2] = fmaf(v, w.z, pr[4 * j4 + 2]);
      pr[4 * j4 + 3] = fmaf(v, w.w, pr[4 * j4 + 3]);
    }
  }
  if (p == 0) {
    float4* a = (float4*)(Ps + (size_t)n * EF);
    a[0] = make_float4(pr[0], pr[1], pr[2], pr[3]);
    a[1] = make_float4(pr[4], pr[5], pr[6], pr[7]);
    a[2] = make_float4(pr[8], pr[9], pr[10], pr[11]);
    a[3] = make_float4(pr[12], pr[13], pr[14], pr[15]);
    float4* b = (float4*)(Pd + (size_t)n * EF);
    b[0] = make_float4(pr[16], pr[17], pr[18], pr[19]);
    b[1] = make_float4(pr[20], pr[21], pr[22], pr[23]);
    b[2] = make_float4(pr[24], pr[25], pr[26], pr[27]);
    b[3] = make_float4(pr[28], pr[29], pr[30], pr[31]);
  } else {
    float4* h = (float4*)(hpart + (size_t)n * NF);
#pragma unroll
    for (int j4 = 0; j4 < 8; ++j4)
      h[j4] = make_float4(pr[4 * j4], pr[4 * j4 + 1], pr[4 * j4 + 2], pr[4 * j4 + 3]);
  }
}

// ---------------------------------------------------------------------------
// edge-role helpers (verified round-5 bodies, parameterized)
// ---------------------------------------------------------------------------
__device__ __forceinline__ void edge_stage_raw(
    const float* __restrict__ e_src, int base, int end, int t, float* sZ) {
  int q = base + t;
  if (q >= end) return;
  const float4* ep = (const float4*)(e_src + (size_t)q * EF);
  float4 v0 = ep[0], v1 = ep[1], v2 = ep[2], v3 = ep[3];
  float* zr = sZ + t * ZSTR;
  zr[0] = v0.x; zr[1] = v0.y; zr[2] = v0.z; zr[3] = v0.w;
  zr[4] = v1.x; zr[5] = v1.y; zr[6] = v1.z; zr[7] = v1.w;
  zr[8] = v2.x; zr[9] = v2.y; zr[10] = v2.z; zr[11] = v2.w;
  zr[12] = v3.x; zr[13] = v3.y; zr[14] = v3.z; zr[15] = v3.w;
}

__device__ __forceinline__ void edge_compute(
    const float* __restrict__ e_src, float* __restrict__ e_dst,
    const float* __restrict__ Ps_cur, const float* __restrict__ Pd_cur,
    const float* sWC, const float* sBC, float* sZ,
    int base, int end, int s_reg, int d_reg, int t, bool store_e) {
  int q = base + t;
  if (q >= end) return;
  float e[EF];
  const float4* ebp = (const float4*)(e_src + (size_t)q * EF);
#pragma unroll
  for (int k4 = 0; k4 < 4; ++k4) {
    float4 v = ebp[k4];
    e[4 * k4] = v.x; e[4 * k4 + 1] = v.y; e[4 * k4 + 2] = v.z; e[4 * k4 + 3] = v.w;
  }
  const float4* ps = (const float4*)(Ps_cur + (size_t)s_reg * EF);
  const float4* pd = (const float4*)(Pd_cur + (size_t)d_reg * EF);
  float z[EF];
#pragma unroll
  for (int i4 = 0; i4 < 4; ++i4) {
    float4 a = ps[i4], bb = pd[i4];
    z[4 * i4 + 0] = sBC[4 * i4 + 0] + a.x + bb.x;
    z[4 * i4 + 1] = sBC[4 * i4 + 1] + a.y + bb.y;
    z[4 * i4 + 2] = sBC[4 * i4 + 2] + a.z + bb.z;
    z[4 * i4 + 3] = sBC[4 * i4 + 3] + a.w + bb.w;
  }
#pragma unroll
  for (int k = 0; k < EF; ++k) {
    float v = e[k];
    const float4* wr = (const float4*)(sWC + k * EF);
#pragma unroll
    for (int i4 = 0; i4 < 4; ++i4) {
      float4 w = wr[i4];
      z[4 * i4 + 0] = fmaf(v, w.x, z[4 * i4 + 0]);
      z[4 * i4 + 1] = fmaf(v, w.y, z[4 * i4 + 1]);
      z[4 * i4 + 2] = fmaf(v, w.z, z[4 * i4 + 2]);
      z[4 * i4 + 3] = fmaf(v, w.w, z[4 * i4 + 3]);
    }
  }
#pragma unroll
  for (int j = 0; j < EF; ++j) z[j] = sigmoidf_(z[j]);
  if (store_e) {
    float4* obp = (float4*)(e_dst + (size_t)q * EF);
#pragma unroll
    for (int i4 = 0; i4 < 4; ++i4)
      obp[i4] = make_float4(z[4 * i4], z[4 * i4 + 1], z[4 * i4 + 2], z[4 * i4 + 3]);
  }
  float* zr = sZ + t * ZSTR;
#pragma unroll
  for (int j = 0; j < EF; ++j) zr[j] = z[j];
}

__device__ __forceinline__ void edge_reduce(
    const float* sZ, const int* __restrict__ off, float* __restrict__ aggW,
    int base, int end, int d_first, int span, int t) {
  int f = (t & 7) * 2;
  for (int r = t >> 3; r < span; r += 32) {
    int dd = d_first + r;
    int lo = off[dd], hi = off[dd + 1];
    int ql = lo > base ? lo : base;
    int qh = hi < end ? hi : end;
    float s0 = 0.f, s1 = 0.f;
    for (int qq = ql; qq < qh; ++qq) {
      const float* zr = sZ + (qq - base) * ZSTR + f;
      s0 += zr[0]; s1 += zr[1];
    }
    float* grow = aggW + (size_t)dd * EF + f;
    if (lo >= base && hi <= end) { grow[0] = s0; grow[1] = s1; }
    else { atomicAdd(&grow[0], s0); atomicAdd(&grow[1], s1); }
  }
}

// ---------------------------------------------------------------------------
// Persistent kernel (plain launch + software barrier).
// Roles over 1024 blocks: roleA = b (node if b<235, else edge chunk b-235);
// roleB = b+1024 if <1173 (edge chunk b+789, only for b<149).
// Phase 0: edge roles reduce raw e_b0 -> G0. Phases 1..11: node_i || edge_i
// (round-5 verified dataflow). Tail: node blocks run final pass -> out.
// ---------------------------------------------------------------------------
__global__ void __launch_bounds__(256, 4) persist_kernel(
    float* __restrict__ e_b0, float* __restrict__ e_b1,
    const unsigned short* __restrict__ src_s, const unsigned short* __restrict__ dst_s,
    float* __restrict__ Ps0, float* __restrict__ Pd0,
    float* __restrict__ Ps1, float* __restrict__ Pd1,
    float* __restrict__ hpart, const int* __restrict__ off,
    const float* __restrict__ wbuf,
    float* __restrict__ G0, float* __restrict__ G1,
    float* __restrict__ out, int* __restrict__ bar) {
  __shared__ float sNW[2920];      // sPRJ 2048 | sWnc 512 | sPB 64 | sbvec 32 | sWNF 256 | sBNF 8
  __shared__ float sEW[272];       // sWC 256 | sBC 16
  __shared__ float sZ[256 * ZSTR]; // 4352
  int t = threadIdx.x;
  int b = blockIdx.x;
  float* PsA[2] = {Ps0, Ps1};
  float* PdA[2] = {Pd0, Pd1};
  float* EbA[2] = {e_b0, e_b1};
  float* GAv[2] = {G0, G1};

  bool hasNode = (b < NB2_GRID);
  bool hasEA = (b >= NB2_GRID);
  bool hasEB = (b + NBLK_P < NROLES);

  // ---- stage weights (once) ----
  if (hasNode) {
    for (int i = t; i < 2048; i += 256) sNW[i] = wbuf[W_SD + i];
    for (int i = t; i < 512; i += 256) sNW[2048 + i] = wbuf[W_NC + i];
    if (t < 64) sNW[2560 + t] = wbuf[B_SD + t];
    if (t < 32) sNW[2624 + t] = wbuf[B_VEC + t];
    sNW[2656 + t] = wbuf[W_NF + t];
    if (t < 8) sNW[2912 + t] = wbuf[B_NF + t];
  }
  sEW[t] = wbuf[W_COMB + t];
  if (t < EF) sEW[256 + t] = wbuf[B_COMB + t];

  // ---- cache per-role state ----
  int n = 0, p = t & 1; bool actN = false; float dg = 0.f;
  if (hasNode) {
    n = b * 128 + (t >> 1);
    actN = (n < N_NODES);
    if (actN) dg = (float)(off[n + 1] - off[n]);
  }
  int baseA = 0, endA = 0, sA = 0, dA = 0, dfA = 0, spanA = 0;
  if (hasEA) {
    int c = b - NB2_GRID;
    baseA = c * 256; endA = baseA + 256; if (endA > N_EDGES) endA = N_EDGES;
    int q = baseA + t;
    if (q < endA) { sA = src_s[q]; dA = dst_s[q]; }
    dfA = dst_s[baseA];
    spanA = (int)dst_s[endA - 1] - dfA + 1;
  }
  int baseB = 0, endB = 0, sB = 0, dB = 0, dfB = 0, spanB = 0;
  if (hasEB) {
    int c = b + NBLK_P - NB2_GRID;
    baseB = c * 256; endB = baseB + 256; if (endB > N_EDGES) endB = N_EDGES;
    int q = baseB + t;
    if (q < endB) { sB = src_s[q]; dB = dst_s[q]; }
    dfB = dst_s[baseB];
    spanB = (int)dst_s[endB - 1] - dfB + 1;
  }
  __syncthreads();

  // ---- phase 0: G0 = segsum(raw e_b0) by edge roles ----
  if (hasEA) {
    edge_stage_raw(e_b0, baseA, endA, t, sZ);
    __syncthreads();
    edge_reduce(sZ, off, G0, baseA, endA, dfA, spanA, t);
  }
  if (hasEB) {
    __syncthreads();
    edge_stage_raw(e_b0, baseB, endB, t, sZ);
    __syncthreads();
    edge_reduce(sZ, off, G0, baseB, endB, dfB, spanB, t);
  }
  gbarrier(bar, 1);

  // ---- phases 1..11 ----
  for (int i = 1; i <= 11; ++i) {
    const float* e_src = EbA[(i + 1) & 1];
    float* e_dst = EbA[i & 1];
    const float* Ps_cur = PsA[i & 1];
    const float* Pd_cur = PdA[i & 1];
    float* aggW = GAv[i & 1];
    bool notlast = (i < 11);

    if (hasNode && actN) {
      float* aggR = GAv[(i + 1) & 1];
      float* ar = aggR + (size_t)n * EF + 8 * p;
      float4 a0 = ((const float4*)ar)[0];
      float4 a1 = ((const float4*)ar)[1];
      if (notlast) {   // zero for edge_{i+1}; dead after pass 11
        ((float4*)ar)[0] = make_float4(0.f, 0.f, 0.f, 0.f);
        ((float4*)ar)[1] = make_float4(0.f, 0.f, 0.f, 0.f);
      }
      float s8[8] = {a0.x, a0.y, a0.z, a0.w, a1.x, a1.y, a1.z, a1.w};

      float z[NF];
      if (p == 0) {
        const float4* hp = (const float4*)(hpart + (size_t)n * NF);
#pragma unroll
        for (int j4 = 0; j4 < 8; ++j4) {
          float4 v = hp[j4];
          z[4 * j4] = v.x; z[4 * j4 + 1] = v.y;
          z[4 * j4 + 2] = v.z; z[4 * j4 + 3] = v.w;
        }
      } else {
#pragma unroll
        for (int j = 0; j < NF; ++j) z[j] = dg * sNW[2624 + j];
      }
#pragma unroll
      for (int k = 0; k < 8; ++k) {
        float v = s8[k];
        const float4* wr = (const float4*)(sNW + 2048 + (8 * p + k) * NF);
#pragma unroll
        for (int j4 = 0; j4 < 8; ++j4) {
          float4 w = wr[j4];
          z[4 * j4 + 0] = fmaf(v, w.x, z[4 * j4 + 0]);
          z[4 * j4 + 1] = fmaf(v, w.y, z[4 * j4 + 1]);
          z[4 * j4 + 2] = fmaf(v, w.z, z[4 * j4 + 2]);
          z[4 * j4 + 3] = fmaf(v, w.w, z[4 * j4 + 3]);
        }
      }
#pragma unroll
      for (int j = 0; j < NF; ++j) z[j] += __shfl_xor(z[j], 1, 64);
#pragma unroll
      for (int j = 0; j < NF; ++j) z[j] = sigmoidf_(z[j]);

      float pr[NF];
      const float* pb = sNW + 2560 + p * 32;
#pragma unroll
      for (int j = 0; j < NF; ++j) pr[j] = pb[j];
      const float* wbase = sNW + p * 1024;
      for (int k = 0; k < NF; ++k) {
        float v = z[k];
        const float4* wr = (const float4*)(wbase + k * NF);
#pragma unroll
        for (int j4 = 0; j4 < 8; ++j4) {
          float4 w = wr[j4];
          pr[4 * j4 + 0] = fmaf(v, w.x, pr[4 * j4 + 0]);
          pr[4 * j4 + 1] = fmaf(v, w.y, pr[4 * j4 + 1]);
          pr[4 * j4 + 2] = fmaf(v, w.z, pr[4 * j4 + 2]);
          pr[4 * j4 + 3] = fmaf(v, w.w, pr[4 * j4 + 3]);
        }
      }
      if (p == 0) {
        if (notlast) {   // pass-11 P writes dead (no edge pass 12)
          float* Ps_next = PsA[(i + 1) & 1];
          float* Pd_next = PdA[(i + 1) & 1];
          float4* a = (float4*)(Ps_next + (size_t)n * EF);
          a[0] = make_float4(pr[0], pr[1], pr[2], pr[3]);
          a[1] = make_float4(pr[4], pr[5], pr[6], pr[7]);
          a[2] = make_float4(pr[8], pr[9], pr[10], pr[11]);
          a[3] = make_float4(pr[12], pr[13], pr[14], pr[15]);
          float4* bb = (float4*)(Pd_next + (size_t)n * EF);
          bb[0] = make_float4(pr[16], pr[17], pr[18], pr[19]);
          bb[1] = make_float4(pr[20], pr[21], pr[22], pr[23]);
          bb[2] = make_float4(pr[24], pr[25], pr[26], pr[27]);
          bb[3] = make_float4(pr[28], pr[29], pr[30], pr[31]);
        }
      } else {
        float4* h = (float4*)(hpart + (size_t)n * NF);
#pragma unroll
        for (int j4 = 0; j4 < 8; ++j4)
          h[j4] = make_float4(pr[4 * j4], pr[4 * j4 + 1],
                              pr[4 * j4 + 2], pr[4 * j4 + 3]);
      }
    }
    if (hasEA) {
      edge_compute(e_src, e_dst, Ps_cur, Pd_cur, sEW, sEW + 256, sZ,
                   baseA, endA, sA, dA, t, notlast);
      __syncthreads();
      edge_reduce(sZ, off, aggW, baseA, endA, dfA, spanA, t);
    }
    if (hasEB) {
      __syncthreads();   // previous reduce (or node part) vs sZ overwrite
      edge_compute(e_src, e_dst, Ps_cur, Pd_cur, sEW, sEW + 256, sZ,
                   baseB, endB, sB, dB, t, notlast);
      __syncthreads();
      edge_reduce(sZ, off, aggW, baseB, endB, dfB, spanB, t);
    }
    gbarrier(bar, 1 + i);
  }

  // ---- final node pass (iter 12) + output head ----
  if (hasNode && actN) {
    const float4* ap = (const float4*)(G1 + (size_t)n * EF + 8 * p);
    float4 a0 = ap[0], a1 = ap[1];
    float s8[8] = {a0.x, a0.y, a0.z, a0.w, a1.x, a1.y, a1.z, a1.w};
    float z[NF];
    if (p == 0) {
      const float4* hp = (const float4*)(hpart + (size_t)n * NF);
#pragma unroll
      for (int j4 = 0; j4 < 8; ++j4) {
        float4 v = hp[j4];
        z[4 * j4] = v.x; z[4 * j4 + 1] = v.y;
        z[4 * j4 + 2] = v.z; z[4 * j4 + 3] = v.w;
      }
    } else {
#pragma unroll
      for (int j = 0; j < NF; ++j) z[j] = dg * sNW[2624 + j];
    }
#pragma unroll
    for (int k = 0; k < 8; ++k) {
      float v = s8[k];
      const float4* wr = (const float4*)(sNW + 2048 + (8 * p + k) * NF);
#pragma unroll
      for (int j4 = 0; j4 < 8; ++j4) {
        float4 w = wr[j4];
        z[4 * j4 + 0] = fmaf(v, w.x, z[4 * j4 + 0]);
        z[4 * j4 + 1] = fmaf(v, w.y, z[4 * j4 + 1]);
        z[4 * j4 + 2] = fmaf(v, w.z, z[4 * j4 + 2]);
        z[4 * j4 + 3] = fmaf(v, w.w, z[4 * j4 + 3]);
      }
    }
#pragma unroll
    for (int j = 0; j < NF; ++j) z[j] += __shfl_xor(z[j], 1, 64);
#pragma unroll
    for (int j = 0; j < NF; ++j) z[j] = sigmoidf_(z[j]);

    float o[NC];
    float pm = (p == 0) ? 1.0f : 0.0f;
#pragma unroll
    for (int c = 0; c < NC; ++c) o[c] = pm * sNW[2912 + c];
    for (int k = 0; k < 16; ++k) {
      float v = z[16 * p + k];
      const float* wr = sNW + 2656 + (16 * p + k) * NC;
#pragma unroll
      for (int c = 0; c < NC; ++c) o[c] = fmaf(v, wr[c], o[c]);
    }
#pragma unroll
    for (int c = 0; c < NC; ++c) o[c] += __shfl_xor(o[c], 1, 64);
    if (p == 0) {
      float4* op = (float4*)(out + (size_t)n * NC);
      op[0] = make_float4(o[0], o[1], o[2], o[3]);
      op[1] = make_float4(o[4], o[5], o[6], o[7]);
    }
  }
}

// ---------------------------------------------------------------------------
extern "C" void kernel_launch(void* const* d_in, const int* in_sizes, int n_in,
                              void* d_out, int out_size, void* d_ws, size_t ws_size,
                              hipStream_t stream) {
  const float* node_feat = (const float*)d_in[0];
  const float* edge_feat = (const float*)d_in[1];
  const int*   src = (const int*)d_in[2];
  const int*   dst = (const int*)d_in[3];
  const float* Wn  = (const float*)d_in[4];
  const float* bn  = (const float*)d_in[5];
  const float* We  = (const float*)d_in[6];
  const float* be  = (const float*)d_in[7];
  const float* Wem = (const float*)d_in[8];
  const float* bem = (const float*)d_in[9];
  const float* Wnm = (const float*)d_in[10];
  const float* bnm = (const float*)d_in[11];
  const float* Wfc = (const float*)d_in[12];
  const float* bfc = (const float*)d_in[13];
  float* out = (float*)d_out;

  float* ws    = (float*)d_ws;
  float* e_b0  = ws;                                   // 3,840,000 f
  float* e_b1  = e_b0 + (size_t)N_EDGES * EF;          // 3,840,000 f
  float* hpart = e_b1 + (size_t)N_EDGES * EF;          //   960,000 f
  float* Ps0   = hpart + (size_t)N_NODES * NF;         //   480,000 f
  float* Pd0   = Ps0 + (size_t)N_NODES * EF;
  float* Ps1   = Pd0 + (size_t)N_NODES * EF;
  float* Pd1   = Ps1 + (size_t)N_NODES * EF;
  float* G0    = Pd1 + (size_t)N_NODES * EF;           //   480,000 f
  float* G1    = G0 + (size_t)N_NODES * EF;            //   480,000 f
  float* wbuf  = G1 + (size_t)N_NODES * EF;            //     4,096 f
  int* cnt     = (int*)(wbuf + 4096);                  //    30,000 i
  int* off     = cnt + N_NODES;                        //    30,001 i
  int* cursor  = off + N_NODES + 1;                    //    30,000 i
  unsigned short* src_s = (unsigned short*)(cursor + N_NODES);  // 240,000 u16
  unsigned short* dst_s = src_s + N_EDGES;                      // 240,000 u16
  int* bar     = (int*)(dst_s + N_EDGES);              //         2 i

  // --- preamble: counting sort + weight folding; zero agg buffers ---
  hipMemsetAsync(cnt, 0, (size_t)N_NODES * sizeof(int), stream);
  hipMemsetAsync(G0, 0, (size_t)2 * N_NODES * EF * sizeof(float), stream);
  hist_pre_kernel<<<EB_GRID + 1, 256, 0, stream>>>(
      dst, cnt, Wn, bn, We, be, Wem, bem, Wnm, bnm, Wfc, bfc, wbuf, bar);
  scan_kernel<<<1, 1024, 0, stream>>>(cnt, off, cursor);
  scatter_init_kernel<<<EB_GRID + NB2_GRID, 256, 0, stream>>>(
      edge_feat, src, dst, cursor, src_s, dst_s, e_b0,
      node_feat, wbuf, Ps1, Pd1, hpart);

  // --- persistent kernel: prologue-agg + 11 fused passes + final ---
  persist_kernel<<<NBLK_P, 256, 0, stream>>>(
      e_b0, e_b1, src_s, dst_s, Ps0, Pd0, Ps1, Pd1,
      hpart, off, wbuf, G0, G1, out, bar);
}

// Round 8
// 1285.690 us; speedup vs baseline: 2.1180x; 2.1180x over previous
//
#include <hip/hip_runtime.h>

#define N_NODES 30000
#define N_EDGES 240000
#define NF 32
#define EF 16
#define HF 64
#define NC 8

#define EB_GRID  938   // preamble scatter grid (256-edge chunks)
#define NB2_GRID 235   // (2*N_NODES + 255) / 256
#define ZSTR     17    // sZ row stride (odd -> free 2-way bank aliasing)

#define NODE_B   235   // node-role blocks (128 nodes each, 2 thr/node)
#define EDGE_B   469   // edge-role blocks (512 edges each, 2 edges/thread)
#define NBLK_P   (NODE_B + EDGE_B)   // 704 <= 768 guaranteed-resident

// wbuf layout (float offsets)
#define W_COMB 0
#define B_COMB 256
#define W_NC   272
#define B_VEC  784
#define W_SD   816
#define W_NB   1840
#define B_SD   2864
#define B_NB   2896
#define W_NF   2928
#define B_NF   3184

// precompute LDS staging layout (float offsets)
#define LWn   0
#define LWe   2048
#define LWem  3072
#define LWnm  6144
#define LWfc  10240
#define Lbn   10752
#define Lbe   10816
#define Lbem  10880
#define Lbnm  10896
#define Lbfc  10928
#define LTOT  10936

__device__ __forceinline__ float sigmoidf_(float x) {
  return 1.0f / (1.0f + __expf(-x));
}

// ---------------------------------------------------------------------------
// software global barrier. Arrival: ACQ_REL fetch_add (release = wb dirty L2;
// acquire = inv stale lines ONCE). Spin: RELAXED atomic loads (coherent point
// access, NO cache-wide invalidate — round-7's per-iteration ACQUIRE inv was
// the 8x FETCH blowup). One ACQUIRE load after exit for formal ordering.
// ---------------------------------------------------------------------------
__device__ __forceinline__ void gbarrier(int* bar, int phase) {
  __syncthreads();
  if (threadIdx.x == 0) {
    int prev = __hip_atomic_fetch_add(&bar[0], 1, __ATOMIC_ACQ_REL,
                                      __HIP_MEMORY_SCOPE_AGENT);
    if (prev == NBLK_P - 1) {
      __hip_atomic_store(&bar[0], 0, __ATOMIC_RELAXED, __HIP_MEMORY_SCOPE_AGENT);
      __hip_atomic_store(&bar[1], phase, __ATOMIC_RELEASE, __HIP_MEMORY_SCOPE_AGENT);
    } else {
      int v;
      do {
        __builtin_amdgcn_s_sleep(4);
        v = __hip_atomic_load(&bar[1], __ATOMIC_RELAXED, __HIP_MEMORY_SCOPE_AGENT);
      } while (v < phase);
      (void)__hip_atomic_load(&bar[1], __ATOMIC_ACQUIRE, __HIP_MEMORY_SCOPE_AGENT);
    }
  }
  __syncthreads();
}

// ---------------------------------------------------------------------------
// hist (blocks 0..EB-1) + precompute (block EB) — LDS-staged weight folding.
// Block EB thread 0 also zeroes barrier state (re-zeroed every graph replay).
// ---------------------------------------------------------------------------
__global__ void __launch_bounds__(256) hist_pre_kernel(
    const int* __restrict__ dst, int* __restrict__ cnt,
    const float* __restrict__ Wn, const float* __restrict__ bn,
    const float* __restrict__ We, const float* __restrict__ be,
    const float* __restrict__ Wem, const float* __restrict__ bem,
    const float* __restrict__ Wnm, const float* __restrict__ bnm,
    const float* __restrict__ Wfc, const float* __restrict__ bfc,
    float* __restrict__ wbuf, int* __restrict__ bar) {
  __shared__ float sW[LTOT];
  if (blockIdx.x < EB_GRID) {
    int e = blockIdx.x * 256 + threadIdx.x;
    if (e < N_EDGES) atomicAdd(&cnt[dst[e]], 1);
    return;
  }
  int tid = threadIdx.x;
  if (tid == 0) { bar[0] = 0; bar[1] = 0; }
  for (int i = tid; i < 2048; i += 256) sW[LWn + i] = Wn[i];
  for (int i = tid; i < 1024; i += 256) sW[LWe + i] = We[i];
  for (int i = tid; i < 3072; i += 256) sW[LWem + i] = Wem[i];
  for (int i = tid; i < 4096; i += 256) sW[LWnm + i] = Wnm[i];
  for (int i = tid; i < 512; i += 256) sW[LWfc + i] = Wfc[i];
  if (tid < 64) sW[Lbn + tid] = bn[tid];
  if (tid < 64) sW[Lbe + tid] = be[tid];
  if (tid < 16) sW[Lbem + tid] = bem[tid];
  if (tid < 32) sW[Lbnm + tid] = bnm[tid];
  if (tid < 8)  sW[Lbfc + tid] = bfc[tid];
  __syncthreads();
  {  // Wcomb
    int r = tid >> 4, c = tid & 15;
    float acc = 0.f;
    for (int j = 0; j < HF; ++j)
      acc = fmaf(sW[LWe + r * HF + j], sW[LWem + (HF + j) * EF + c], acc);
    wbuf[W_COMB + tid] = acc;
  }
  for (int idx = tid; idx < EF * NF; idx += 256) {  // Wnc
    int r = idx >> 5, c = idx & 31;
    float acc = 0.f;
    for (int j = 0; j < HF; ++j)
      acc = fmaf(sW[LWe + r * HF + j], sW[LWnm + j * NF + c], acc);
    wbuf[W_NC + idx] = acc;
  }
  for (int idx = tid; idx < NF * NF; idx += 256) {  // WSD
    int r = idx >> 5, c = idx & 31;
    float acc = 0.f;
    if (c < EF) {
      for (int j = 0; j < HF; ++j)
        acc = fmaf(sW[LWn + r * HF + j], sW[LWem + j * EF + c], acc);
    } else {
      int cc = c - EF;
      for (int j = 0; j < HF; ++j)
        acc = fmaf(sW[LWn + r * HF + j], sW[LWem + (2 * HF + j) * EF + cc], acc);
    }
    wbuf[W_SD + idx] = acc;
  }
  for (int idx = tid; idx < NF * NF; idx += 256) {  // WnB
    int r = idx >> 5, c = idx & 31;
    float acc = 0.f;
    for (int j = 0; j < HF; ++j)
      acc = fmaf(sW[LWn + r * HF + j], sW[LWnm + (HF + j) * NF + c], acc);
    wbuf[W_NB + idx] = acc;
  }
  if (tid < NF * NC) {  // Wnf
    int r = tid >> 3, c = tid & 7;
    float acc = 0.f;
    for (int j = 0; j < HF; ++j)
      acc = fmaf(sW[LWn + r * HF + j], sW[LWfc + j * NC + c], acc);
    wbuf[W_NF + tid] = acc;
  }
  if (tid < EF) {  // bcomb
    float acc = sW[Lbem + tid];
    for (int j = 0; j < HF; ++j)
      acc = fmaf(sW[Lbe + j], sW[LWem + (HF + j) * EF + tid], acc);
    wbuf[B_COMB + tid] = acc;
  }
  if (tid < NF) {  // bvec
    float acc = 0.f;
    for (int j = 0; j < HF; ++j)
      acc = fmaf(sW[Lbe + j], sW[LWnm + j * NF + tid], acc);
    wbuf[B_VEC + tid] = acc;
  }
  if (tid < NF) {  // bSD
    float acc = 0.f;
    if (tid < EF) {
      for (int j = 0; j < HF; ++j)
        acc = fmaf(sW[Lbn + j], sW[LWem + j * EF + tid], acc);
    } else {
      int cc = tid - EF;
      for (int j = 0; j < HF; ++j)
        acc = fmaf(sW[Lbn + j], sW[LWem + (2 * HF + j) * EF + cc], acc);
    }
    wbuf[B_SD + tid] = acc;
  }
  if (tid < NF) {  // bNB
    float acc = sW[Lbnm + tid];
    for (int j = 0; j < HF; ++j)
      acc = fmaf(sW[Lbn + j], sW[LWnm + (HF + j) * NF + tid], acc);
    wbuf[B_NB + tid] = acc;
  }
  if (tid < NC) {  // bnf
    float acc = sW[Lbfc + tid];
    for (int j = 0; j < HF; ++j)
      acc = fmaf(sW[Lbn + j], sW[LWfc + j * NC + tid], acc);
    wbuf[B_NF + tid] = acc;
  }
}

// exclusive scan of cnt[30000] -> off[30001], cursor = copy of off
__global__ void __launch_bounds__(1024) scan_kernel(
    const int* __restrict__ cnt, int* __restrict__ off, int* __restrict__ cursor) {
  __shared__ int part[1024];
  int t = threadIdx.x;
  const int CH = (N_NODES + 1023) / 1024;   // 30
  int base = t * CH;
  int lc[CH];
  int sum = 0;
  for (int i = 0; i < CH; ++i) {
    int idx = base + i;
    lc[i] = (idx < N_NODES) ? cnt[idx] : 0;
    sum += lc[i];
  }
  part[t] = sum;
  __syncthreads();
  for (int ofs = 1; ofs < 1024; ofs <<= 1) {
    int v = (t >= ofs) ? part[t - ofs] : 0;
    __syncthreads();
    part[t] += v;
    __syncthreads();
  }
  int run = (t == 0) ? 0 : part[t - 1];
  for (int i = 0; i < CH; ++i) {
    int idx = base + i;
    if (idx < N_NODES) {
      off[idx] = run;
      cursor[idx] = run;
      run += lc[i];
    }
  }
  if (t == 1023) off[N_NODES] = part[1023];
}

// ---------------------------------------------------------------------------
// scatter (blocks 0..EB-1) + init_proj (blocks EB..EB+NB2-1).
// ---------------------------------------------------------------------------
__global__ void __launch_bounds__(256) scatter_init_kernel(
    const float* __restrict__ edge_feat, const int* __restrict__ src,
    const int* __restrict__ dst, int* __restrict__ cursor,
    unsigned short* __restrict__ src_s, unsigned short* __restrict__ dst_s,
    float* __restrict__ e_buf,
    const float* __restrict__ node_feat, const float* __restrict__ wbuf,
    float* __restrict__ Ps, float* __restrict__ Pd, float* __restrict__ hpart) {
  if (blockIdx.x < EB_GRID) {
    int e = blockIdx.x * 256 + threadIdx.x;
    if (e >= N_EDGES) return;
    int d = dst[e];
    int pos = atomicAdd(&cursor[d], 1);
    src_s[pos] = (unsigned short)src[e];
    dst_s[pos] = (unsigned short)d;
    const float4* ep = (const float4*)(edge_feat + (size_t)e * EF);
    float4* op = (float4*)(e_buf + (size_t)pos * EF);
    op[0] = ep[0]; op[1] = ep[1]; op[2] = ep[2]; op[3] = ep[3];
    return;
  }
  __shared__ float sPRJ[2048];
  __shared__ float sPB[64];
  for (int i = threadIdx.x; i < 2048; i += 256) sPRJ[i] = wbuf[W_SD + i];
  if (threadIdx.x < 64) sPB[threadIdx.x] = wbuf[B_SD + threadIdx.x];
  __syncthreads();
  int gid = (blockIdx.x - EB_GRID) * 256 + threadIdx.x;
  int n = gid >> 1, p = gid & 1;
  if (n >= N_NODES) return;
  float x[NF];
  const float4* xp = (const float4*)(node_feat + (size_t)n * NF);
#pragma unroll
  for (int k4 = 0; k4 < 8; ++k4) {
    float4 v = xp[k4];
    x[4 * k4] = v.x; x[4 * k4 + 1] = v.y; x[4 * k4 + 2] = v.z; x[4 * k4 + 3] = v.w;
  }
  float pr[NF];
  const float* pb = sPB + p * 32;
#pragma unroll
  for (int j = 0; j < NF; ++j) pr[j] = pb[j];
  const float* wbase = sPRJ + p * 1024;
  for (int k = 0; k < NF; ++k) {
    float v = x[k];
    const float4* wr = (const float4*)(wbase + k * NF);
#pragma unroll
    for (int j4 = 0; j4 < 8; ++j4) {
      float4 w = wr[j4];
      pr[4 * j4 + 0] = fmaf(v, w.x, pr[4 * j4 + 0]);
      pr[4 * j4 + 1] = fmaf(v, w.y, pr[4 * j4 + 1]);
      pr[4 * j4 + 2] = fmaf(v, w.z, pr[4 * j4 + 2]);
      pr[4 * j4 + 3] = fmaf(v, w.w, pr[4 * j4 + 3]);
    }
  }
  if (p == 0) {
    float4* a = (float4*)(Ps + (size_t)n * EF);
    a[0] = make_float4(pr[0], pr[1], pr[2], pr[3]);
    a[1] = make_float4(pr[4], pr[5], pr[6], pr[7]);
    a[2] = make_float4(pr[8], pr[9], pr[10], pr[11]);
    a[3] = make_float4(pr[12], pr[13], pr[14], pr[15]);
    float4* b = (float4*)(Pd + (size_t)n * EF);
    b[0] = make_float4(pr[16], pr[17], pr[18], pr[19]);
    b[1] = make_float4(pr[20], pr[21], pr[22], pr[23]);
    b[2] = make_float4(pr[24], pr[25], pr[26], pr[27]);
    b[3] = make_float4(pr[28], pr[29], pr[30], pr[31]);
  } else {
    float4* h = (float4*)(hpart + (size_t)n * NF);
#pragma unroll
    for (int j4 = 0; j4 < 8; ++j4)
      h[j4] = make_float4(pr[4 * j4], pr[4 * j4 + 1], pr[4 * j4 + 2], pr[4 * j4 + 3]);
  }
}

// ---------------------------------------------------------------------------
// conflict-free two-phase segment reduce over one 256-row half of sZ
// (verified round-5 logic, parameterized by half bounds).
// ---------------------------------------------------------------------------
__device__ __forceinline__ void edge_reduce(
    const float* sZ, const int* __restrict__ off, float* __restrict__ aggW,
    int baseH, int endH, int d_first, int span, int t) {
  int f = (t & 7) * 2;
  for (int r = t >> 3; r < span; r += 32) {
    int dd = d_first + r;
    int lo = off[dd], hi = off[dd + 1];
    int ql = lo > baseH ? lo : baseH;
    int qh = hi < endH ? hi : endH;
    float s0 = 0.f, s1 = 0.f;
    for (int qq = ql; qq < qh; ++qq) {
      const float* zr = sZ + (qq - baseH) * ZSTR + f;
      s0 += zr[0]; s1 += zr[1];
    }
    float* grow = aggW + (size_t)dd * EF + f;
    if (lo >= baseH && hi <= endH) { grow[0] = s0; grow[1] = s1; }
    else { atomicAdd(&grow[0], s0); atomicAdd(&grow[1], s1); }
  }
}

// edge math on register-resident e state; updates e in place, stages to sZ.
__device__ __forceinline__ void edge_phase_half(
    float (&e)[EF],
    const float* __restrict__ Ps_cur, const float* __restrict__ Pd_cur,
    const float* sWC, const float* sBC, float* sZ,
    int s_reg, int d_reg, int t, bool act) {
  if (!act) return;
  const float4* ps = (const float4*)(Ps_cur + (size_t)s_reg * EF);
  const float4* pd = (const float4*)(Pd_cur + (size_t)d_reg * EF);
  float z[EF];
#pragma unroll
  for (int i4 = 0; i4 < 4; ++i4) {
    float4 a = ps[i4], bb = pd[i4];
    z[4 * i4 + 0] = sBC[4 * i4 + 0] + a.x + bb.x;
    z[4 * i4 + 1] = sBC[4 * i4 + 1] + a.y + bb.y;
    z[4 * i4 + 2] = sBC[4 * i4 + 2] + a.z + bb.z;
    z[4 * i4 + 3] = sBC[4 * i4 + 3] + a.w + bb.w;
  }
#pragma unroll
  for (int k = 0; k < EF; ++k) {
    float v = e[k];
    const float4* wr = (const float4*)(sWC + k * EF);
#pragma unroll
    for (int i4 = 0; i4 < 4; ++i4) {
      float4 w = wr[i4];
      z[4 * i4 + 0] = fmaf(v, w.x, z[4 * i4 + 0]);
      z[4 * i4 + 1] = fmaf(v, w.y, z[4 * i4 + 1]);
      z[4 * i4 + 2] = fmaf(v, w.z, z[4 * i4 + 2]);
      z[4 * i4 + 3] = fmaf(v, w.w, z[4 * i4 + 3]);
    }
  }
  float* zr = sZ + t * ZSTR;
#pragma unroll
  for (int j = 0; j < EF; ++j) { e[j] = sigmoidf_(z[j]); zr[j] = e[j]; }
}

// ---------------------------------------------------------------------------
// Persistent kernel (plain launch + software barrier).
// 704 blocks: [0,235) node role (128 nodes, 2 thr/node);
// [235,704) edge role (512 edges, 2 edges/thread, e-state IN REGISTERS for
// all 12 phases — no e_b global traffic after the initial load).
// Phase 0: edge roles reduce raw e -> G0. Phases 1..11: node_i || edge_i
// (round-5 verified dataflow). Tail: node blocks run final pass -> out.
// __launch_bounds__(256,3): VGPR<=168 -> 3 blocks/CU guaranteed, 768 >= 704.
// ---------------------------------------------------------------------------
__global__ void __launch_bounds__(256, 3) persist_kernel(
    const float* __restrict__ e_b0,
    const unsigned short* __restrict__ src_s, const unsigned short* __restrict__ dst_s,
    float* __restrict__ Ps0, float* __restrict__ Pd0,
    float* __restrict__ Ps1, float* __restrict__ Pd1,
    float* __restrict__ hpart, const int* __restrict__ off,
    const float* __restrict__ wbuf,
    float* __restrict__ G0, float* __restrict__ G1,
    float* __restrict__ out, int* __restrict__ bar) {
  __shared__ float smem[4640];   // node: 2920 used; edge: 272 + 4352 = 4624
  int t = threadIdx.x;
  int b = blockIdx.x;
  float* PsA[2] = {Ps0, Ps1};
  float* PdA[2] = {Pd0, Pd1};
  float* GAv[2] = {G0, G1};

  if (b < NODE_B) {
    // ================= NODE ROLE (verified round-7 body) =================
    float* sNW = smem;  // sPRJ 2048 | sWnc 512 | sPB 64 | sbvec 32 | sWNF 256 | sBNF 8
    for (int i = t; i < 2048; i += 256) sNW[i] = wbuf[W_SD + i];
    for (int i = t; i < 512; i += 256) sNW[2048 + i] = wbuf[W_NC + i];
    if (t < 64) sNW[2560 + t] = wbuf[B_SD + t];
    if (t < 32) sNW[2624 + t] = wbuf[B_VEC + t];
    sNW[2656 + t] = wbuf[W_NF + t];
    if (t < 8) sNW[2912 + t] = wbuf[B_NF + t];
    __syncthreads();
    int n = b * 128 + (t >> 1), p = t & 1;
    bool actN = (n < N_NODES);
    float dg = 0.f;
    if (actN) dg = (float)(off[n + 1] - off[n]);

    gbarrier(bar, 1);   // phase 0: edge roles build G0

    for (int i = 1; i <= 11; ++i) {
      bool notlast = (i < 11);
      if (actN) {
        float* aggR = GAv[(i + 1) & 1];
        float* ar = aggR + (size_t)n * EF + 8 * p;
        float4 a0 = ((const float4*)ar)[0];
        float4 a1 = ((const float4*)ar)[1];
        if (notlast) {
          ((float4*)ar)[0] = make_float4(0.f, 0.f, 0.f, 0.f);
          ((float4*)ar)[1] = make_float4(0.f, 0.f, 0.f, 0.f);
        }
        float s8[8] = {a0.x, a0.y, a0.z, a0.w, a1.x, a1.y, a1.z, a1.w};

        float z[NF];
        if (p == 0) {
          const float4* hp = (const float4*)(hpart + (size_t)n * NF);
#pragma unroll
          for (int j4 = 0; j4 < 8; ++j4) {
            float4 v = hp[j4];
            z[4 * j4] = v.x; z[4 * j4 + 1] = v.y;
            z[4 * j4 + 2] = v.z; z[4 * j4 + 3] = v.w;
          }
        } else {
#pragma unroll
          for (int j = 0; j < NF; ++j) z[j] = dg * sNW[2624 + j];
        }
#pragma unroll
        for (int k = 0; k < 8; ++k) {
          float v = s8[k];
          const float4* wr = (const float4*)(sNW + 2048 + (8 * p + k) * NF);
#pragma unroll
          for (int j4 = 0; j4 < 8; ++j4) {
            float4 w = wr[j4];
            z[4 * j4 + 0] = fmaf(v, w.x, z[4 * j4 + 0]);
            z[4 * j4 + 1] = fmaf(v, w.y, z[4 * j4 + 1]);
            z[4 * j4 + 2] = fmaf(v, w.z, z[4 * j4 + 2]);
            z[4 * j4 + 3] = fmaf(v, w.w, z[4 * j4 + 3]);
          }
        }
#pragma unroll
        for (int j = 0; j < NF; ++j) z[j] += __shfl_xor(z[j], 1, 64);
#pragma unroll
        for (int j = 0; j < NF; ++j) z[j] = sigmoidf_(z[j]);

        float pr[NF];
        const float* pb = sNW + 2560 + p * 32;
#pragma unroll
        for (int j = 0; j < NF; ++j) pr[j] = pb[j];
        const float* wbase = sNW + p * 1024;
        for (int k = 0; k < NF; ++k) {
          float v = z[k];
          const float4* wr = (const float4*)(wbase + k * NF);
#pragma unroll
          for (int j4 = 0; j4 < 8; ++j4) {
            float4 w = wr[j4];
            pr[4 * j4 + 0] = fmaf(v, w.x, pr[4 * j4 + 0]);
            pr[4 * j4 + 1] = fmaf(v, w.y, pr[4 * j4 + 1]);
            pr[4 * j4 + 2] = fmaf(v, w.z, pr[4 * j4 + 2]);
            pr[4 * j4 + 3] = fmaf(v, w.w, pr[4 * j4 + 3]);
          }
        }
        if (p == 0) {
          if (notlast) {
            float* Ps_next = PsA[(i + 1) & 1];
            float* Pd_next = PdA[(i + 1) & 1];
            float4* a = (float4*)(Ps_next + (size_t)n * EF);
            a[0] = make_float4(pr[0], pr[1], pr[2], pr[3]);
            a[1] = make_float4(pr[4], pr[5], pr[6], pr[7]);
            a[2] = make_float4(pr[8], pr[9], pr[10], pr[11]);
            a[3] = make_float4(pr[12], pr[13], pr[14], pr[15]);
            float4* bb = (float4*)(Pd_next + (size_t)n * EF);
            bb[0] = make_float4(pr[16], pr[17], pr[18], pr[19]);
            bb[1] = make_float4(pr[20], pr[21], pr[22], pr[23]);
            bb[2] = make_float4(pr[24], pr[25], pr[26], pr[27]);
            bb[3] = make_float4(pr[28], pr[29], pr[30], pr[31]);
          }
        } else {
          float4* h = (float4*)(hpart + (size_t)n * NF);
#pragma unroll
          for (int j4 = 0; j4 < 8; ++j4)
            h[j4] = make_float4(pr[4 * j4], pr[4 * j4 + 1],
                                pr[4 * j4 + 2], pr[4 * j4 + 3]);
        }
      }
      gbarrier(bar, 1 + i);
    }

    // ---- final node pass (iter 12) + output head ----
    if (actN) {
      const float4* ap = (const float4*)(G1 + (size_t)n * EF + 8 * p);
      float4 a0 = ap[0], a1 = ap[1];
      float s8[8] = {a0.x, a0.y, a0.z, a0.w, a1.x, a1.y, a1.z, a1.w};
      float z[NF];
      if (p == 0) {
        const float4* hp = (const float4*)(hpart + (size_t)n * NF);
#pragma unroll
        for (int j4 = 0; j4 < 8; ++j4) {
          float4 v = hp[j4];
          z[4 * j4] = v.x; z[4 * j4 + 1] = v.y;
          z[4 * j4 + 2] = v.z; z[4 * j4 + 3] = v.w;
        }
      } else {
#pragma unroll
        for (int j = 0; j < NF; ++j) z[j] = dg * sNW[2624 + j];
      }
#pragma unroll
      for (int k = 0; k < 8; ++k) {
        float v = s8[k];
        const float4* wr = (const float4*)(sNW + 2048 + (8 * p + k) * NF);
#pragma unroll
        for (int j4 = 0; j4 < 8; ++j4) {
          float4 w = wr[j4];
          z[4 * j4 + 0] = fmaf(v, w.x, z[4 * j4 + 0]);
          z[4 * j4 + 1] = fmaf(v, w.y, z[4 * j4 + 1]);
          z[4 * j4 + 2] = fmaf(v, w.z, z[4 * j4 + 2]);
          z[4 * j4 + 3] = fmaf(v, w.w, z[4 * j4 + 3]);
        }
      }
#pragma unroll
      for (int j = 0; j < NF; ++j) z[j] += __shfl_xor(z[j], 1, 64);
#pragma unroll
      for (int j = 0; j < NF; ++j) z[j] = sigmoidf_(z[j]);

      float o[NC];
      float pm = (p == 0) ? 1.0f : 0.0f;
#pragma unroll
      for (int c = 0; c < NC; ++c) o[c] = pm * sNW[2912 + c];
      for (int k = 0; k < 16; ++k) {
        float v = z[16 * p + k];
        const float* wr = sNW + 2656 + (16 * p + k) * NC;
#pragma unroll
        for (int c = 0; c < NC; ++c) o[c] = fmaf(v, wr[c], o[c]);
      }
#pragma unroll
      for (int c = 0; c < NC; ++c) o[c] += __shfl_xor(o[c], 1, 64);
      if (p == 0) {
        float4* op = (float4*)(out + (size_t)n * NC);
        op[0] = make_float4(o[0], o[1], o[2], o[3]);
        op[1] = make_float4(o[4], o[5], o[6], o[7]);
      }
    }
  } else {
    // ================= EDGE ROLE (e-state in registers) =================
    float* sWC = smem;          // 256
    float* sBC = smem + 256;    // 16
    float* sZ  = smem + 272;    // 256*17 = 4352
    sWC[t] = wbuf[W_COMB + t];
    if (t < EF) sBC[t] = wbuf[B_COMB + t];

    int c = b - NODE_B;
    int base = c * 512;
    int end = base + 512; if (end > N_EDGES) end = N_EDGES;
    int cnt = end - base;              // >= 384 for all chunks
    int h0n = 256;                     // half 0 rows (cnt >= 256 always)
    int h1n = cnt - 256;               // half 1 rows (128..256)
    int q0 = base + t;
    int q1 = base + 256 + t;
    bool act1 = (t < h1n);
    int s0 = src_s[q0], d0 = dst_s[q0];
    int s1 = 0, d1 = 0;
    if (act1) { s1 = src_s[q1]; d1 = dst_s[q1]; }
    int df0 = dst_s[base];
    int span0 = (int)dst_s[base + h0n - 1] - df0 + 1;
    int df1 = (int)dst_s[base + 256];
    int span1 = (int)dst_s[end - 1] - df1 + 1;

    // load e-state into registers (ONLY global e access in the kernel)
    float e0[EF], e1[EF];
    {
      const float4* p4 = (const float4*)(e_b0 + (size_t)q0 * EF);
      float4 v0 = p4[0], v1 = p4[1], v2 = p4[2], v3 = p4[3];
      e0[0]=v0.x; e0[1]=v0.y; e0[2]=v0.z; e0[3]=v0.w;
      e0[4]=v1.x; e0[5]=v1.y; e0[6]=v1.z; e0[7]=v1.w;
      e0[8]=v2.x; e0[9]=v2.y; e0[10]=v2.z; e0[11]=v2.w;
      e0[12]=v3.x; e0[13]=v3.y; e0[14]=v3.z; e0[15]=v3.w;
    }
    if (act1) {
      const float4* p4 = (const float4*)(e_b0 + (size_t)q1 * EF);
      float4 v0 = p4[0], v1 = p4[1], v2 = p4[2], v3 = p4[3];
      e1[0]=v0.x; e1[1]=v0.y; e1[2]=v0.z; e1[3]=v0.w;
      e1[4]=v1.x; e1[5]=v1.y; e1[6]=v1.z; e1[7]=v1.w;
      e1[8]=v2.x; e1[9]=v2.y; e1[10]=v2.z; e1[11]=v2.w;
      e1[12]=v3.x; e1[13]=v3.y; e1[14]=v3.z; e1[15]=v3.w;
    } else {
#pragma unroll
      for (int j = 0; j < EF; ++j) e1[j] = 0.f;
    }
    __syncthreads();

    // ---- phase 0: G0 = segsum(raw e) ----
    {
      float* zr = sZ + t * ZSTR;
#pragma unroll
      for (int j = 0; j < EF; ++j) zr[j] = e0[j];
      __syncthreads();
      edge_reduce(sZ, off, G0, base, base + h0n, df0, span0, t);
      __syncthreads();
      if (act1) {
#pragma unroll
        for (int j = 0; j < EF; ++j) zr[j] = e1[j];
      }
      __syncthreads();
      edge_reduce(sZ, off, G0, base + 256, end, df1, span1, t);
    }
    gbarrier(bar, 1);

    // ---- 11 edge passes ----
    for (int i = 1; i <= 11; ++i) {
      const float* Ps_cur = PsA[i & 1];
      const float* Pd_cur = PdA[i & 1];
      float* aggW = GAv[i & 1];
      edge_phase_half(e0, Ps_cur, Pd_cur, sWC, sBC, sZ, s0, d0, t, true);
      __syncthreads();
      edge_reduce(sZ, off, aggW, base, base + h0n, df0, span0, t);
      __syncthreads();
      edge_phase_half(e1, Ps_cur, Pd_cur, sWC, sBC, sZ, s1, d1, t, act1);
      __syncthreads();
      edge_reduce(sZ, off, aggW, base + 256, end, df1, span1, t);
      gbarrier(bar, 1 + i);
    }
    // final pass: edge blocks idle
  }
}

// ---------------------------------------------------------------------------
extern "C" void kernel_launch(void* const* d_in, const int* in_sizes, int n_in,
                              void* d_out, int out_size, void* d_ws, size_t ws_size,
                              hipStream_t stream) {
  const float* node_feat = (const float*)d_in[0];
  const float* edge_feat = (const float*)d_in[1];
  const int*   src = (const int*)d_in[2];
  const int*   dst = (const int*)d_in[3];
  const float* Wn  = (const float*)d_in[4];
  const float* bn  = (const float*)d_in[5];
  const float* We  = (const float*)d_in[6];
  const float* be  = (const float*)d_in[7];
  const float* Wem = (const float*)d_in[8];
  const float* bem = (const float*)d_in[9];
  const float* Wnm = (const float*)d_in[10];
  const float* bnm = (const float*)d_in[11];
  const float* Wfc = (const float*)d_in[12];
  const float* bfc = (const float*)d_in[13];
  float* out = (float*)d_out;

  float* ws    = (float*)d_ws;
  float* e_b0  = ws;                                   // 3,840,000 f
  float* e_b1  = e_b0 + (size_t)N_EDGES * EF;          // (unused; layout kept)
  float* hpart = e_b1 + (size_t)N_EDGES * EF;          //   960,000 f
  float* Ps0   = hpart + (size_t)N_NODES * NF;         //   480,000 f
  float* Pd0   = Ps0 + (size_t)N_NODES * EF;
  float* Ps1   = Pd0 + (size_t)N_NODES * EF;
  float* Pd1   = Ps1 + (size_t)N_NODES * EF;
  float* G0    = Pd1 + (size_t)N_NODES * EF;           //   480,000 f
  float* G1    = G0 + (size_t)N_NODES * EF;            //   480,000 f
  float* wbuf  = G1 + (size_t)N_NODES * EF;            //     4,096 f
  int* cnt     = (int*)(wbuf + 4096);                  //    30,000 i
  int* off     = cnt + N_NODES;                        //    30,001 i
  int* cursor  = off + N_NODES + 1;                    //    30,000 i
  unsigned short* src_s = (unsigned short*)(cursor + N_NODES);  // 240,000 u16
  unsigned short* dst_s = src_s + N_EDGES;                      // 240,000 u16
  int* bar     = (int*)(dst_s + N_EDGES);              //         2 i

  // --- preamble: counting sort + weight folding; zero agg buffers ---
  hipMemsetAsync(cnt, 0, (size_t)N_NODES * sizeof(int), stream);
  hipMemsetAsync(G0, 0, (size_t)2 * N_NODES * EF * sizeof(float), stream);
  hist_pre_kernel<<<EB_GRID + 1, 256, 0, stream>>>(
      dst, cnt, Wn, bn, We, be, Wem, bem, Wnm, bnm, Wfc, bfc, wbuf, bar);
  scan_kernel<<<1, 1024, 0, stream>>>(cnt, off, cursor);
  scatter_init_kernel<<<EB_GRID + NB2_GRID, 256, 0, stream>>>(
      edge_feat, src, dst, cursor, src_s, dst_s, e_b0,
      node_feat, wbuf, Ps1, Pd1, hpart);

  // --- persistent kernel: prologue-agg + 11 fused passes + final ---
  persist_kernel<<<NBLK_P, 256, 0, stream>>>(
      e_b0, src_s, dst_s, Ps0, Pd0, Ps1, Pd1,
      hpart, off, wbuf, G0, G1, out, bar);
}

// Round 9
// 646.530 us; speedup vs baseline: 4.2119x; 1.9886x over previous
//
#include <hip/hip_runtime.h>

#define N_NODES 30000
#define N_EDGES 240000
#define NF 32
#define EF 16
#define HF 64
#define NC 8

#define EB_GRID  938   // preamble scatter grid (256-edge chunks)
#define NB2_GRID 235   // (2*N_NODES + 255) / 256
#define ZSTR     17    // sZ row stride (odd -> free 2-way bank aliasing)

#define NODE_B   235   // node-role blocks (128 nodes each, 2 thr/node)
#define EDGE_B   469   // edge-role blocks (512 edges each, 2 edges/thread)
#define NBLK_P   (NODE_B + EDGE_B)   // 704 <= 768 guaranteed-resident

// barrier layout (ints): bar[0] = flag; slot[b] = bar[16 + b*16] (64B/line)
#define BAR_INTS ((NBLK_P + 1) * 16)

// wbuf layout (float offsets)
#define W_COMB 0
#define B_COMB 256
#define W_NC   272
#define B_VEC  784
#define W_SD   816
#define W_NB   1840
#define B_SD   2864
#define B_NB   2896
#define W_NF   2928
#define B_NF   3184

// precompute LDS staging layout (float offsets)
#define LWn   0
#define LWe   2048
#define LWem  3072
#define LWnm  6144
#define LWfc  10240
#define Lbn   10752
#define Lbe   10816
#define Lbem  10880
#define Lbnm  10896
#define Lbfc  10928
#define LTOT  10936

__device__ __forceinline__ float sigmoidf_(float x) {
  return 1.0f / (1.0f + __expf(-x));
}

// ---------------------------------------------------------------------------
// Distributed store-slot barrier: NO RMW chain (round-8's 704 serialized
// ACQ_REL fetch_adds on one line were ~60-90us/phase). Each block
// release-stores its own slot (parallel, separate lines); master (block 0)
// polls slots with 256 threads (relaxed), one acquire FENCE, release-stores
// the flag; workers relaxed-spin flag + one acquire load (round-8-verified).
// ---------------------------------------------------------------------------
__device__ __forceinline__ void gbarrier(int* bar, int phase, bool skip_wait) {
  __syncthreads();
  int t = threadIdx.x;
  if (blockIdx.x == 0) {
    for (int idx = 1 + t; idx < NBLK_P; idx += 256) {
      while (__hip_atomic_load(&bar[16 + idx * 16], __ATOMIC_RELAXED,
                               __HIP_MEMORY_SCOPE_AGENT) < phase)
        __builtin_amdgcn_s_sleep(1);
    }
    __syncthreads();
    if (t == 0) {
      __builtin_amdgcn_fence(__ATOMIC_ACQUIRE, "agent");
      __hip_atomic_store(&bar[0], phase, __ATOMIC_RELEASE,
                         __HIP_MEMORY_SCOPE_AGENT);
    }
  } else {
    if (t == 0) {
      __hip_atomic_store(&bar[16 + blockIdx.x * 16], phase, __ATOMIC_RELEASE,
                         __HIP_MEMORY_SCOPE_AGENT);
      if (!skip_wait) {
        while (__hip_atomic_load(&bar[0], __ATOMIC_RELAXED,
                                 __HIP_MEMORY_SCOPE_AGENT) < phase)
          __builtin_amdgcn_s_sleep(1);
        (void)__hip_atomic_load(&bar[0], __ATOMIC_ACQUIRE,
                                __HIP_MEMORY_SCOPE_AGENT);
      }
    }
  }
  __syncthreads();
}

// ---------------------------------------------------------------------------
// hist (blocks 0..EB-1) + precompute (block EB) — LDS-staged weight folding.
// Block EB also zeroes ALL barrier state (re-zeroed every graph replay).
// ---------------------------------------------------------------------------
__global__ void __launch_bounds__(256) hist_pre_kernel(
    const int* __restrict__ dst, int* __restrict__ cnt,
    const float* __restrict__ Wn, const float* __restrict__ bn,
    const float* __restrict__ We, const float* __restrict__ be,
    const float* __restrict__ Wem, const float* __restrict__ bem,
    const float* __restrict__ Wnm, const float* __restrict__ bnm,
    const float* __restrict__ Wfc, const float* __restrict__ bfc,
    float* __restrict__ wbuf, int* __restrict__ bar) {
  __shared__ float sW[LTOT];
  if (blockIdx.x < EB_GRID) {
    int e = blockIdx.x * 256 + threadIdx.x;
    if (e < N_EDGES) atomicAdd(&cnt[dst[e]], 1);
    return;
  }
  int tid = threadIdx.x;
  for (int i = tid; i < BAR_INTS; i += 256) bar[i] = 0;
  for (int i = tid; i < 2048; i += 256) sW[LWn + i] = Wn[i];
  for (int i = tid; i < 1024; i += 256) sW[LWe + i] = We[i];
  for (int i = tid; i < 3072; i += 256) sW[LWem + i] = Wem[i];
  for (int i = tid; i < 4096; i += 256) sW[LWnm + i] = Wnm[i];
  for (int i = tid; i < 512; i += 256) sW[LWfc + i] = Wfc[i];
  if (tid < 64) sW[Lbn + tid] = bn[tid];
  if (tid < 64) sW[Lbe + tid] = be[tid];
  if (tid < 16) sW[Lbem + tid] = bem[tid];
  if (tid < 32) sW[Lbnm + tid] = bnm[tid];
  if (tid < 8)  sW[Lbfc + tid] = bfc[tid];
  __syncthreads();
  {  // Wcomb
    int r = tid >> 4, c = tid & 15;
    float acc = 0.f;
    for (int j = 0; j < HF; ++j)
      acc = fmaf(sW[LWe + r * HF + j], sW[LWem + (HF + j) * EF + c], acc);
    wbuf[W_COMB + tid] = acc;
  }
  for (int idx = tid; idx < EF * NF; idx += 256) {  // Wnc
    int r = idx >> 5, c = idx & 31;
    float acc = 0.f;
    for (int j = 0; j < HF; ++j)
      acc = fmaf(sW[LWe + r * HF + j], sW[LWnm + j * NF + c], acc);
    wbuf[W_NC + idx] = acc;
  }
  for (int idx = tid; idx < NF * NF; idx += 256) {  // WSD
    int r = idx >> 5, c = idx & 31;
    float acc = 0.f;
    if (c < EF) {
      for (int j = 0; j < HF; ++j)
        acc = fmaf(sW[LWn + r * HF + j], sW[LWem + j * EF + c], acc);
    } else {
      int cc = c - EF;
      for (int j = 0; j < HF; ++j)
        acc = fmaf(sW[LWn + r * HF + j], sW[LWem + (2 * HF + j) * EF + cc], acc);
    }
    wbuf[W_SD + idx] = acc;
  }
  for (int idx = tid; idx < NF * NF; idx += 256) {  // WnB
    int r = idx >> 5, c = idx & 31;
    float acc = 0.f;
    for (int j = 0; j < HF; ++j)
      acc = fmaf(sW[LWn + r * HF + j], sW[LWnm + (HF + j) * NF + c], acc);
    wbuf[W_NB + idx] = acc;
  }
  if (tid < NF * NC) {  // Wnf
    int r = tid >> 3, c = tid & 7;
    float acc = 0.f;
    for (int j = 0; j < HF; ++j)
      acc = fmaf(sW[LWn + r * HF + j], sW[LWfc + j * NC + c], acc);
    wbuf[W_NF + tid] = acc;
  }
  if (tid < EF) {  // bcomb
    float acc = sW[Lbem + tid];
    for (int j = 0; j < HF; ++j)
      acc = fmaf(sW[Lbe + j], sW[LWem + (HF + j) * EF + tid], acc);
    wbuf[B_COMB + tid] = acc;
  }
  if (tid < NF) {  // bvec
    float acc = 0.f;
    for (int j = 0; j < HF; ++j)
      acc = fmaf(sW[Lbe + j], sW[LWnm + j * NF + tid], acc);
    wbuf[B_VEC + tid] = acc;
  }
  if (tid < NF) {  // bSD
    float acc = 0.f;
    if (tid < EF) {
      for (int j = 0; j < HF; ++j)
        acc = fmaf(sW[Lbn + j], sW[LWem + j * EF + tid], acc);
    } else {
      int cc = tid - EF;
      for (int j = 0; j < HF; ++j)
        acc = fmaf(sW[Lbn + j], sW[LWem + (2 * HF + j) * EF + cc], acc);
    }
    wbuf[B_SD + tid] = acc;
  }
  if (tid < NF) {  // bNB
    float acc = sW[Lbnm + tid];
    for (int j = 0; j < HF; ++j)
      acc = fmaf(sW[Lbn + j], sW[LWnm + (HF + j) * NF + tid], acc);
    wbuf[B_NB + tid] = acc;
  }
  if (tid < NC) {  // bnf
    float acc = sW[Lbfc + tid];
    for (int j = 0; j < HF; ++j)
      acc = fmaf(sW[Lbn + j], sW[LWfc + j * NC + tid], acc);
    wbuf[B_NF + tid] = acc;
  }
}

// exclusive scan of cnt[30000] -> off[30001], cursor = copy of off
__global__ void __launch_bounds__(1024) scan_kernel(
    const int* __restrict__ cnt, int* __restrict__ off, int* __restrict__ cursor) {
  __shared__ int part[1024];
  int t = threadIdx.x;
  const int CH = (N_NODES + 1023) / 1024;   // 30
  int base = t * CH;
  int lc[CH];
  int sum = 0;
  for (int i = 0; i < CH; ++i) {
    int idx = base + i;
    lc[i] = (idx < N_NODES) ? cnt[idx] : 0;
    sum += lc[i];
  }
  part[t] = sum;
  __syncthreads();
  for (int ofs = 1; ofs < 1024; ofs <<= 1) {
    int v = (t >= ofs) ? part[t - ofs] : 0;
    __syncthreads();
    part[t] += v;
    __syncthreads();
  }
  int run = (t == 0) ? 0 : part[t - 1];
  for (int i = 0; i < CH; ++i) {
    int idx = base + i;
    if (idx < N_NODES) {
      off[idx] = run;
      cursor[idx] = run;
      run += lc[i];
    }
  }
  if (t == 1023) off[N_NODES] = part[1023];
}

// ---------------------------------------------------------------------------
// scatter (blocks 0..EB-1) + init_proj (blocks EB..EB+NB2-1).
// ---------------------------------------------------------------------------
__global__ void __launch_bounds__(256) scatter_init_kernel(
    const float* __restrict__ edge_feat, const int* __restrict__ src,
    const int* __restrict__ dst, int* __restrict__ cursor,
    unsigned short* __restrict__ src_s, unsigned short* __restrict__ dst_s,
    float* __restrict__ e_buf,
    const float* __restrict__ node_feat, const float* __restrict__ wbuf,
    float* __restrict__ Ps, float* __restrict__ Pd, float* __restrict__ hpart) {
  if (blockIdx.x < EB_GRID) {
    int e = blockIdx.x * 256 + threadIdx.x;
    if (e >= N_EDGES) return;
    int d = dst[e];
    int pos = atomicAdd(&cursor[d], 1);
    src_s[pos] = (unsigned short)src[e];
    dst_s[pos] = (unsigned short)d;
    const float4* ep = (const float4*)(edge_feat + (size_t)e * EF);
    float4* op = (float4*)(e_buf + (size_t)pos * EF);
    op[0] = ep[0]; op[1] = ep[1]; op[2] = ep[2]; op[3] = ep[3];
    return;
  }
  __shared__ float sPRJ[2048];
  __shared__ float sPB[64];
  for (int i = threadIdx.x; i < 2048; i += 256) sPRJ[i] = wbuf[W_SD + i];
  if (threadIdx.x < 64) sPB[threadIdx.x] = wbuf[B_SD + threadIdx.x];
  __syncthreads();
  int gid = (blockIdx.x - EB_GRID) * 256 + threadIdx.x;
  int n = gid >> 1, p = gid & 1;
  if (n >= N_NODES) return;
  float x[NF];
  const float4* xp = (const float4*)(node_feat + (size_t)n * NF);
#pragma unroll
  for (int k4 = 0; k4 < 8; ++k4) {
    float4 v = xp[k4];
    x[4 * k4] = v.x; x[4 * k4 + 1] = v.y; x[4 * k4 + 2] = v.z; x[4 * k4 + 3] = v.w;
  }
  float pr[NF];
  const float* pb = sPB + p * 32;
#pragma unroll
  for (int j = 0; j < NF; ++j) pr[j] = pb[j];
  const float* wbase = sPRJ + p * 1024;
  for (int k = 0; k < NF; ++k) {
    float v = x[k];
    const float4* wr = (const float4*)(wbase + k * NF);
#pragma unroll
    for (int j4 = 0; j4 < 8; ++j4) {
      float4 w = wr[j4];
      pr[4 * j4 + 0] = fmaf(v, w.x, pr[4 * j4 + 0]);
      pr[4 * j4 + 1] = fmaf(v, w.y, pr[4 * j4 + 1]);
      pr[4 * j4 + 2] = fmaf(v, w.z, pr[4 * j4 + 2]);
      pr[4 * j4 + 3] = fmaf(v, w.w, pr[4 * j4 + 3]);
    }
  }
  if (p == 0) {
    float4* a = (float4*)(Ps + (size_t)n * EF);
    a[0] = make_float4(pr[0], pr[1], pr[2], pr[3]);
    a[1] = make_float4(pr[4], pr[5], pr[6], pr[7]);
    a[2] = make_float4(pr[8], pr[9], pr[10], pr[11]);
    a[3] = make_float4(pr[12], pr[13], pr[14], pr[15]);
    float4* b = (float4*)(Pd + (size_t)n * EF);
    b[0] = make_float4(pr[16], pr[17], pr[18], pr[19]);
    b[1] = make_float4(pr[20], pr[21], pr[22], pr[23]);
    b[2] = make_float4(pr[24], pr[25], pr[26], pr[27]);
    b[3] = make_float4(pr[28], pr[29], pr[30], pr[31]);
  } else {
    float4* h = (float4*)(hpart + (size_t)n * NF);
#pragma unroll
    for (int j4 = 0; j4 < 8; ++j4)
      h[j4] = make_float4(pr[4 * j4], pr[4 * j4 + 1], pr[4 * j4 + 2], pr[4 * j4 + 3]);
  }
}

// ---------------------------------------------------------------------------
// conflict-free two-phase segment reduce over one 256-row half of sZ.
// Span [d_lo, d_hi) closes gaps: deg-0/gap nodes get plain-stored 0.
// atomicAdd only for nodes whose range crosses the half bounds (those are
// exactly the 256-boundary-crossing nodes, pre-zeroed by node side);
// atomicAdd(0) on unzeroed nodes is order-safe (adds nothing).
// ---------------------------------------------------------------------------
__device__ __forceinline__ void edge_reduce(
    const float* sZ, const int* __restrict__ off, float* __restrict__ aggW,
    int baseH, int endH, int d_lo, int d_hi, int t) {
  int f = (t & 7) * 2;
  for (int r = t >> 3; d_lo + r < d_hi; r += 32) {
    int dd = d_lo + r;
    int lo = off[dd], hi = off[dd + 1];
    int ql = lo > baseH ? lo : baseH;
    int qh = hi < endH ? hi : endH;
    float s0 = 0.f, s1 = 0.f;
    for (int qq = ql; qq < qh; ++qq) {
      const float* zr = sZ + (qq - baseH) * ZSTR + f;
      s0 += zr[0]; s1 += zr[1];
    }
    float* grow = aggW + (size_t)dd * EF + f;
    if (lo >= baseH && hi <= endH) { grow[0] = s0; grow[1] = s1; }
    else { atomicAdd(&grow[0], s0); atomicAdd(&grow[1], s1); }
  }
}

// edge math on register-resident e state; updates e in place, stages to sZ.
__device__ __forceinline__ void edge_phase_half(
    float (&e)[EF],
    const float* __restrict__ Ps_cur, const float* __restrict__ Pd_cur,
    const float* sWC, const float* sBC, float* sZ,
    int s_reg, int d_reg, int t, bool act) {
  if (!act) return;
  const float4* ps = (const float4*)(Ps_cur + (size_t)s_reg * EF);
  const float4* pd = (const float4*)(Pd_cur + (size_t)d_reg * EF);
  float z[EF];
#pragma unroll
  for (int i4 = 0; i4 < 4; ++i4) {
    float4 a = ps[i4], bb = pd[i4];
    z[4 * i4 + 0] = sBC[4 * i4 + 0] + a.x + bb.x;
    z[4 * i4 + 1] = sBC[4 * i4 + 1] + a.y + bb.y;
    z[4 * i4 + 2] = sBC[4 * i4 + 2] + a.z + bb.z;
    z[4 * i4 + 3] = sBC[4 * i4 + 3] + a.w + bb.w;
  }
#pragma unroll
  for (int k = 0; k < EF; ++k) {
    float v = e[k];
    const float4* wr = (const float4*)(sWC + k * EF);
#pragma unroll
    for (int i4 = 0; i4 < 4; ++i4) {
      float4 w = wr[i4];
      z[4 * i4 + 0] = fmaf(v, w.x, z[4 * i4 + 0]);
      z[4 * i4 + 1] = fmaf(v, w.y, z[4 * i4 + 1]);
      z[4 * i4 + 2] = fmaf(v, w.z, z[4 * i4 + 2]);
      z[4 * i4 + 3] = fmaf(v, w.w, z[4 * i4 + 3]);
    }
  }
  float* zr = sZ + t * ZSTR;
#pragma unroll
  for (int j = 0; j < EF; ++j) { e[j] = sigmoidf_(z[j]); zr[j] = e[j]; }
}

// ---------------------------------------------------------------------------
// Persistent kernel (plain launch + distributed store-slot barrier).
// 704 blocks: [0,235) node role (128 nodes, 2 thr/node; hpart held in p1's
// registers, exchanged via shfl_xor); [235,704) edge role (512 edges,
// 2 edges/thread, e-state in registers all 12 phases).
// ---------------------------------------------------------------------------
__global__ void __launch_bounds__(256, 3) persist_kernel(
    const float* __restrict__ e_b0,
    const unsigned short* __restrict__ src_s, const unsigned short* __restrict__ dst_s,
    float* __restrict__ Ps0, float* __restrict__ Pd0,
    float* __restrict__ Ps1, float* __restrict__ Pd1,
    float* __restrict__ hpart, const int* __restrict__ off,
    const float* __restrict__ wbuf,
    float* __restrict__ G0, float* __restrict__ G1,
    float* __restrict__ out, int* __restrict__ bar) {
  __shared__ float smem[4640];   // node: 2920 used; edge: 272 + 4352 = 4624
  int t = threadIdx.x;
  int b = blockIdx.x;
  float* PsA[2] = {Ps0, Ps1};
  float* PdA[2] = {Pd0, Pd1};
  float* GAv[2] = {G0, G1};

  if (b < NODE_B) {
    // ================= NODE ROLE =================
    float* sNW = smem;  // sPRJ 2048 | sWnc 512 | sPB 64 | sbvec 32 | sWNF 256 | sBNF 8
    for (int i = t; i < 2048; i += 256) sNW[i] = wbuf[W_SD + i];
    for (int i = t; i < 512; i += 256) sNW[2048 + i] = wbuf[W_NC + i];
    if (t < 64) sNW[2560 + t] = wbuf[B_SD + t];
    if (t < 32) sNW[2624 + t] = wbuf[B_VEC + t];
    sNW[2656 + t] = wbuf[W_NF + t];
    if (t < 8) sNW[2912 + t] = wbuf[B_NF + t];
    __syncthreads();
    int n = b * 128 + (t >> 1), p = t & 1;
    bool actN = (n < N_NODES);
    float dg = 0.f;
    bool crossF = false;
    if (actN) {
      int o0 = off[n], o1 = off[n + 1];
      dg = (float)(o1 - o0);
      crossF = (o1 > o0) && ((o0 >> 8) != ((o1 - 1) >> 8));
    }
    // hpart in registers: p1 holds hv[32] (from scatter_init's write)
    float hv[NF];
#pragma unroll
    for (int j = 0; j < NF; ++j) hv[j] = 0.f;
    if (actN && p == 1) {
      const float4* hp = (const float4*)(hpart + (size_t)n * NF);
#pragma unroll
      for (int j4 = 0; j4 < 8; ++j4) {
        float4 v = hp[j4];
        hv[4 * j4] = v.x; hv[4 * j4 + 1] = v.y;
        hv[4 * j4 + 2] = v.z; hv[4 * j4 + 3] = v.w;
      }
    }

    gbarrier(bar, 1, false);   // phase 0: edge roles build G0

    for (int i = 1; i <= 11; ++i) {
      bool notlast = (i < 11);
      if (actN) {
        float* aggR = GAv[(i + 1) & 1];
        float* ar = aggR + (size_t)n * EF + 8 * p;
        float4 a0 = ((const float4*)ar)[0];
        float4 a1 = ((const float4*)ar)[1];
        if (notlast && crossF) {  // zero ONLY boundary-atomic targets
          ((float4*)ar)[0] = make_float4(0.f, 0.f, 0.f, 0.f);
          ((float4*)ar)[1] = make_float4(0.f, 0.f, 0.f, 0.f);
        }
        float s8[8] = {a0.x, a0.y, a0.z, a0.w, a1.x, a1.y, a1.z, a1.w};

        float z[NF];
#pragma unroll
        for (int j = 0; j < NF; ++j) {
          float hvv = __shfl_xor(hv[j], 1, 64);   // p0 <- p1's hpart
          z[j] = (p == 0) ? hvv : dg * sNW[2624 + j];
        }
#pragma unroll
        for (int k = 0; k < 8; ++k) {
          float v = s8[k];
          const float4* wr = (const float4*)(sNW + 2048 + (8 * p + k) * NF);
#pragma unroll
          for (int j4 = 0; j4 < 8; ++j4) {
            float4 w = wr[j4];
            z[4 * j4 + 0] = fmaf(v, w.x, z[4 * j4 + 0]);
            z[4 * j4 + 1] = fmaf(v, w.y, z[4 * j4 + 1]);
            z[4 * j4 + 2] = fmaf(v, w.z, z[4 * j4 + 2]);
            z[4 * j4 + 3] = fmaf(v, w.w, z[4 * j4 + 3]);
          }
        }
#pragma unroll
        for (int j = 0; j < NF; ++j) z[j] += __shfl_xor(z[j], 1, 64);
#pragma unroll
        for (int j = 0; j < NF; ++j) z[j] = sigmoidf_(z[j]);

        float pr[NF];
        const float* pb = sNW + 2560 + p * 32;
#pragma unroll
        for (int j = 0; j < NF; ++j) pr[j] = pb[j];
        const float* wbase = sNW + p * 1024;
        for (int k = 0; k < NF; ++k) {
          float v = z[k];
          const float4* wr = (const float4*)(wbase + k * NF);
#pragma unroll
          for (int j4 = 0; j4 < 8; ++j4) {
            float4 w = wr[j4];
            pr[4 * j4 + 0] = fmaf(v, w.x, pr[4 * j4 + 0]);
            pr[4 * j4 + 1] = fmaf(v, w.y, pr[4 * j4 + 1]);
            pr[4 * j4 + 2] = fmaf(v, w.z, pr[4 * j4 + 2]);
            pr[4 * j4 + 3] = fmaf(v, w.w, pr[4 * j4 + 3]);
          }
        }
        if (p == 0) {
          if (notlast) {   // pass-11 P writes dead (no edge pass 12)
            float* Ps_next = PsA[(i + 1) & 1];
            float* Pd_next = PdA[(i + 1) & 1];
            float4* a = (float4*)(Ps_next + (size_t)n * EF);
            a[0] = make_float4(pr[0], pr[1], pr[2], pr[3]);
            a[1] = make_float4(pr[4], pr[5], pr[6], pr[7]);
            a[2] = make_float4(pr[8], pr[9], pr[10], pr[11]);
            a[3] = make_float4(pr[12], pr[13], pr[14], pr[15]);
            float4* bb = (float4*)(Pd_next + (size_t)n * EF);
            bb[0] = make_float4(pr[16], pr[17], pr[18], pr[19]);
            bb[1] = make_float4(pr[20], pr[21], pr[22], pr[23]);
            bb[2] = make_float4(pr[24], pr[25], pr[26], pr[27]);
            bb[3] = make_float4(pr[28], pr[29], pr[30], pr[31]);
          }
        } else {
#pragma unroll
          for (int j = 0; j < NF; ++j) hv[j] = pr[j];   // hpart stays in regs
        }
      }
      gbarrier(bar, 1 + i, false);
    }

    // ---- final node pass (iter 12) + output head ----
    if (actN) {
      const float4* ap = (const float4*)(G1 + (size_t)n * EF + 8 * p);
      float4 a0 = ap[0], a1 = ap[1];
      float s8[8] = {a0.x, a0.y, a0.z, a0.w, a1.x, a1.y, a1.z, a1.w};
      float z[NF];
#pragma unroll
      for (int j = 0; j < NF; ++j) {
        float hvv = __shfl_xor(hv[j], 1, 64);
        z[j] = (p == 0) ? hvv : dg * sNW[2624 + j];
      }
#pragma unroll
      for (int k = 0; k < 8; ++k) {
        float v = s8[k];
        const float4* wr = (const float4*)(sNW + 2048 + (8 * p + k) * NF);
#pragma unroll
        for (int j4 = 0; j4 < 8; ++j4) {
          float4 w = wr[j4];
          z[4 * j4 + 0] = fmaf(v, w.x, z[4 * j4 + 0]);
          z[4 * j4 + 1] = fmaf(v, w.y, z[4 * j4 + 1]);
          z[4 * j4 + 2] = fmaf(v, w.z, z[4 * j4 + 2]);
          z[4 * j4 + 3] = fmaf(v, w.w, z[4 * j4 + 3]);
        }
      }
#pragma unroll
      for (int j = 0; j < NF; ++j) z[j] += __shfl_xor(z[j], 1, 64);
#pragma unroll
      for (int j = 0; j < NF; ++j) z[j] = sigmoidf_(z[j]);

      float o[NC];
      float pm = (p == 0) ? 1.0f : 0.0f;
#pragma unroll
      for (int c = 0; c < NC; ++c) o[c] = pm * sNW[2912 + c];
      for (int k = 0; k < 16; ++k) {
        float v = z[16 * p + k];
        const float* wr = sNW + 2656 + (16 * p + k) * NC;
#pragma unroll
        for (int c = 0; c < NC; ++c) o[c] = fmaf(v, wr[c], o[c]);
      }
#pragma unroll
      for (int c = 0; c < NC; ++c) o[c] += __shfl_xor(o[c], 1, 64);
      if (p == 0) {
        float4* op = (float4*)(out + (size_t)n * NC);
        op[0] = make_float4(o[0], o[1], o[2], o[3]);
        op[1] = make_float4(o[4], o[5], o[6], o[7]);
      }
    }
  } else {
    // ================= EDGE ROLE (e-state in registers) =================
    float* sWC = smem;          // 256
    float* sBC = smem + 256;    // 16
    float* sZ  = smem + 272;    // 256*17 = 4352
    sWC[t] = wbuf[W_COMB + t];
    if (t < EF) sBC[t] = wbuf[B_COMB + t];

    int c = b - NODE_B;
    int base = c * 512;
    int end = base + 512; if (end > N_EDGES) end = N_EDGES;
    int cnt = end - base;
    int h1n = cnt - 256;
    int q0 = base + t;
    int q1 = base + 256 + t;
    bool act1 = (t < h1n);
    int s0 = src_s[q0], d0 = dst_s[q0];
    int s1 = 0, d1 = 0;
    if (act1) { s1 = src_s[q1]; d1 = dst_s[q1]; }
    // gap-closing spans: half0 covers [df0 (or 0), df1]; half1 covers
    // [df1, next chunk's first dst] (or N_NODES for the last chunk).
    int df0 = dst_s[base];
    int df1 = dst_s[base + 256];
    int dlo0 = (c == 0) ? 0 : df0;
    int dhi0 = df1 + 1;
    int dlo1 = df1;
    int dhi1 = (c + 1 < EDGE_B) ? ((int)dst_s[(c + 1) * 512] + 1) : N_NODES;

    // load e-state into registers (ONLY global e access in the kernel)
    float e0[EF], e1[EF];
    {
      const float4* p4 = (const float4*)(e_b0 + (size_t)q0 * EF);
      float4 v0 = p4[0], v1 = p4[1], v2 = p4[2], v3 = p4[3];
      e0[0]=v0.x; e0[1]=v0.y; e0[2]=v0.z; e0[3]=v0.w;
      e0[4]=v1.x; e0[5]=v1.y; e0[6]=v1.z; e0[7]=v1.w;
      e0[8]=v2.x; e0[9]=v2.y; e0[10]=v2.z; e0[11]=v2.w;
      e0[12]=v3.x; e0[13]=v3.y; e0[14]=v3.z; e0[15]=v3.w;
    }
    if (act1) {
      const float4* p4 = (const float4*)(e_b0 + (size_t)q1 * EF);
      float4 v0 = p4[0], v1 = p4[1], v2 = p4[2], v3 = p4[3];
      e1[0]=v0.x; e1[1]=v0.y; e1[2]=v0.z; e1[3]=v0.w;
      e1[4]=v1.x; e1[5]=v1.y; e1[6]=v1.z; e1[7]=v1.w;
      e1[8]=v2.x; e1[9]=v2.y; e1[10]=v2.z; e1[11]=v2.w;
      e1[12]=v3.x; e1[13]=v3.y; e1[14]=v3.z; e1[15]=v3.w;
    } else {
#pragma unroll
      for (int j = 0; j < EF; ++j) e1[j] = 0.f;
    }
    __syncthreads();

    // ---- phase 0: G0 = segsum(raw e) ----
    {
      float* zr = sZ + t * ZSTR;
#pragma unroll
      for (int j = 0; j < EF; ++j) zr[j] = e0[j];
      __syncthreads();
      edge_reduce(sZ, off, G0, base, base + 256, dlo0, dhi0, t);
      __syncthreads();
      if (act1) {
#pragma unroll
        for (int j = 0; j < EF; ++j) zr[j] = e1[j];
      }
      __syncthreads();
      edge_reduce(sZ, off, G0, base + 256, end, dlo1, dhi1, t);
    }
    gbarrier(bar, 1, false);

    // ---- 11 edge passes ----
    for (int i = 1; i <= 11; ++i) {
      const float* Ps_cur = PsA[i & 1];
      const float* Pd_cur = PdA[i & 1];
      float* aggW = GAv[i & 1];
      edge_phase_half(e0, Ps_cur, Pd_cur, sWC, sBC, sZ, s0, d0, t, true);
      __syncthreads();
      edge_reduce(sZ, off, aggW, base, base + 256, dlo0, dhi0, t);
      __syncthreads();
      edge_phase_half(e1, Ps_cur, Pd_cur, sWC, sBC, sZ, s1, d1, t, act1);
      __syncthreads();
      edge_reduce(sZ, off, aggW, base + 256, end, dlo1, dhi1, t);
      gbarrier(bar, 1 + i, i == 11);   // last: signal and exit (no wait)
    }
  }
}

// ---------------------------------------------------------------------------
extern "C" void kernel_launch(void* const* d_in, const int* in_sizes, int n_in,
                              void* d_out, int out_size, void* d_ws, size_t ws_size,
                              hipStream_t stream) {
  const float* node_feat = (const float*)d_in[0];
  const float* edge_feat = (const float*)d_in[1];
  const int*   src = (const int*)d_in[2];
  const int*   dst = (const int*)d_in[3];
  const float* Wn  = (const float*)d_in[4];
  const float* bn  = (const float*)d_in[5];
  const float* We  = (const float*)d_in[6];
  const float* be  = (const float*)d_in[7];
  const float* Wem = (const float*)d_in[8];
  const float* bem = (const float*)d_in[9];
  const float* Wnm = (const float*)d_in[10];
  const float* bnm = (const float*)d_in[11];
  const float* Wfc = (const float*)d_in[12];
  const float* bfc = (const float*)d_in[13];
  float* out = (float*)d_out;

  float* ws    = (float*)d_ws;
  float* e_b0  = ws;                                   // 3,840,000 f
  float* e_b1  = e_b0 + (size_t)N_EDGES * EF;          // (unused; layout kept)
  float* hpart = e_b1 + (size_t)N_EDGES * EF;          //   960,000 f
  float* Ps0   = hpart + (size_t)N_NODES * NF;         //   480,000 f
  float* Pd0   = Ps0 + (size_t)N_NODES * EF;
  float* Ps1   = Pd0 + (size_t)N_NODES * EF;
  float* Pd1   = Ps1 + (size_t)N_NODES * EF;
  float* G0    = Pd1 + (size_t)N_NODES * EF;           //   480,000 f
  float* G1    = G0 + (size_t)N_NODES * EF;            //   480,000 f
  float* wbuf  = G1 + (size_t)N_NODES * EF;            //     4,096 f
  int* cnt     = (int*)(wbuf + 4096);                  //    30,000 i
  int* off     = cnt + N_NODES;                        //    30,001 i
  int* cursor  = off + N_NODES + 1;                    //    30,000 i
  unsigned short* src_s = (unsigned short*)(cursor + N_NODES);  // 240,000 u16
  unsigned short* dst_s = src_s + N_EDGES;                      // 240,000 u16
  int* bar     = (int*)(dst_s + N_EDGES);              // BAR_INTS ints

  // --- preamble: counting sort + weight folding; zero agg buffers ---
  hipMemsetAsync(cnt, 0, (size_t)N_NODES * sizeof(int), stream);
  hipMemsetAsync(G0, 0, (size_t)2 * N_NODES * EF * sizeof(float), stream);
  hist_pre_kernel<<<EB_GRID + 1, 256, 0, stream>>>(
      dst, cnt, Wn, bn, We, be, Wem, bem, Wnm, bnm, Wfc, bfc, wbuf, bar);
  scan_kernel<<<1, 1024, 0, stream>>>(cnt, off, cursor);
  scatter_init_kernel<<<EB_GRID + NB2_GRID, 256, 0, stream>>>(
      edge_feat, src, dst, cursor, src_s, dst_s, e_b0,
      node_feat, wbuf, Ps1, Pd1, hpart);

  // --- persistent kernel: prologue-agg + 11 fused passes + final ---
  persist_kernel<<<NBLK_P, 256, 0, stream>>>(
      e_b0, src_s, dst_s, Ps0, Pd0, Ps1, Pd1,
      hpart, off, wbuf, G0, G1, out, bar);
}

// Round 10
// 635.757 us; speedup vs baseline: 4.2833x; 1.0169x over previous
//
#include <hip/hip_runtime.h>

#define N_NODES 30000
#define N_EDGES 240000
#define NF 32
#define EF 16
#define HF 64
#define NC 8

#define EB_GRID  938   // preamble scatter grid (256-edge chunks)
#define NB2_GRID 235   // (2*N_NODES + 255) / 256
#define ZSTR     17    // sZ row stride (odd -> free 2-way bank aliasing)

#define NODE_B   235   // node-role blocks (128 nodes each, 2 thr/node)
#define EDGE_B   469   // edge-role blocks (512 edges each, 2 edges/thread)
#define NBLK_P   (NODE_B + EDGE_B)   // 704 <= 768 guaranteed-resident

// barrier layout (ints, 64B-strided lines):
//   flag copies: bar[r*16],       r in [0,64)   — worker b spins flag[b&63]
//   slots:       bar[(64+b)*16],  b in [0,NBLK_P)
#define BAR_INTS ((64 + NBLK_P) * 16)

// wbuf layout (float offsets)
#define W_COMB 0
#define B_COMB 256
#define W_NC   272
#define B_VEC  784
#define W_SD   816
#define W_NB   1840
#define B_SD   2864
#define B_NB   2896
#define W_NF   2928
#define B_NF   3184

// precompute LDS staging layout (float offsets)
#define LWn   0
#define LWe   2048
#define LWem  3072
#define LWnm  6144
#define LWfc  10240
#define Lbn   10752
#define Lbe   10816
#define Lbem  10880
#define Lbnm  10896
#define Lbfc  10928
#define LTOT  10936

__device__ __forceinline__ float sigmoidf_(float x) {
  return 1.0f / (1.0f + __expf(-x));
}

// ---------------------------------------------------------------------------
// Distributed store-slot barrier with REPLICATED broadcast flags.
// Round-8 fix: no RMW chain (parallel release-store slots).
// Round-9 fix: relaxed spin (no per-iteration cache-wide invalidate).
// Round-10 fix: 64 flag copies on separate lines — round-9's single flag
// line had 703 spinners serialized at its coherence point (~33us/phase,
// matching measured overhead). ~11 spinners/line now; backoff s_sleep(8).
// Ordering: producer release-store slot -> master relaxed-load + per-thread
// acquire FENCE (C++ fence-based synchronizes-with) -> block sync ->
// release-store flag copies -> worker relaxed-load + one acquire load.
// ---------------------------------------------------------------------------
__device__ __forceinline__ void gbarrier(int* bar, int phase, bool skip_wait) {
  __syncthreads();
  int t = threadIdx.x;
  if (blockIdx.x == 0) {
    for (int idx = 1 + t; idx < NBLK_P; idx += 256) {
      while (__hip_atomic_load(&bar[(64 + idx) * 16], __ATOMIC_RELAXED,
                               __HIP_MEMORY_SCOPE_AGENT) < phase)
        __builtin_amdgcn_s_sleep(2);
    }
    __builtin_amdgcn_fence(__ATOMIC_ACQUIRE, "agent");
    __syncthreads();
    if (t < 64)
      __hip_atomic_store(&bar[t * 16], phase, __ATOMIC_RELEASE,
                         __HIP_MEMORY_SCOPE_AGENT);
    __syncthreads();
  } else {
    if (t == 0) {
      __hip_atomic_store(&bar[(64 + blockIdx.x) * 16], phase, __ATOMIC_RELEASE,
                         __HIP_MEMORY_SCOPE_AGENT);
      if (!skip_wait) {
        int* flag = &bar[(blockIdx.x & 63) * 16];
        while (__hip_atomic_load(flag, __ATOMIC_RELAXED,
                                 __HIP_MEMORY_SCOPE_AGENT) < phase)
          __builtin_amdgcn_s_sleep(8);
        (void)__hip_atomic_load(flag, __ATOMIC_ACQUIRE,
                                __HIP_MEMORY_SCOPE_AGENT);
      }
    }
    __syncthreads();
  }
}

// ---------------------------------------------------------------------------
// hist (blocks 0..EB-1) + precompute (block EB) — LDS-staged weight folding.
// Block EB also zeroes ALL barrier state (re-zeroed every graph replay).
// ---------------------------------------------------------------------------
__global__ void __launch_bounds__(256) hist_pre_kernel(
    const int* __restrict__ dst, int* __restrict__ cnt,
    const float* __restrict__ Wn, const float* __restrict__ bn,
    const float* __restrict__ We, const float* __restrict__ be,
    const float* __restrict__ Wem, const float* __restrict__ bem,
    const float* __restrict__ Wnm, const float* __restrict__ bnm,
    const float* __restrict__ Wfc, const float* __restrict__ bfc,
    float* __restrict__ wbuf, int* __restrict__ bar) {
  __shared__ float sW[LTOT];
  if (blockIdx.x < EB_GRID) {
    int e = blockIdx.x * 256 + threadIdx.x;
    if (e < N_EDGES) atomicAdd(&cnt[dst[e]], 1);
    return;
  }
  int tid = threadIdx.x;
  for (int i = tid; i < BAR_INTS; i += 256) bar[i] = 0;
  for (int i = tid; i < 2048; i += 256) sW[LWn + i] = Wn[i];
  for (int i = tid; i < 1024; i += 256) sW[LWe + i] = We[i];
  for (int i = tid; i < 3072; i += 256) sW[LWem + i] = Wem[i];
  for (int i = tid; i < 4096; i += 256) sW[LWnm + i] = Wnm[i];
  for (int i = tid; i < 512; i += 256) sW[LWfc + i] = Wfc[i];
  if (tid < 64) sW[Lbn + tid] = bn[tid];
  if (tid < 64) sW[Lbe + tid] = be[tid];
  if (tid < 16) sW[Lbem + tid] = bem[tid];
  if (tid < 32) sW[Lbnm + tid] = bnm[tid];
  if (tid < 8)  sW[Lbfc + tid] = bfc[tid];
  __syncthreads();
  {  // Wcomb
    int r = tid >> 4, c = tid & 15;
    float acc = 0.f;
    for (int j = 0; j < HF; ++j)
      acc = fmaf(sW[LWe + r * HF + j], sW[LWem + (HF + j) * EF + c], acc);
    wbuf[W_COMB + tid] = acc;
  }
  for (int idx = tid; idx < EF * NF; idx += 256) {  // Wnc
    int r = idx >> 5, c = idx & 31;
    float acc = 0.f;
    for (int j = 0; j < HF; ++j)
      acc = fmaf(sW[LWe + r * HF + j], sW[LWnm + j * NF + c], acc);
    wbuf[W_NC + idx] = acc;
  }
  for (int idx = tid; idx < NF * NF; idx += 256) {  // WSD
    int r = idx >> 5, c = idx & 31;
    float acc = 0.f;
    if (c < EF) {
      for (int j = 0; j < HF; ++j)
        acc = fmaf(sW[LWn + r * HF + j], sW[LWem + j * EF + c], acc);
    } else {
      int cc = c - EF;
      for (int j = 0; j < HF; ++j)
        acc = fmaf(sW[LWn + r * HF + j], sW[LWem + (2 * HF + j) * EF + cc], acc);
    }
    wbuf[W_SD + idx] = acc;
  }
  for (int idx = tid; idx < NF * NF; idx += 256) {  // WnB
    int r = idx >> 5, c = idx & 31;
    float acc = 0.f;
    for (int j = 0; j < HF; ++j)
      acc = fmaf(sW[LWn + r * HF + j], sW[LWnm + (HF + j) * NF + c], acc);
    wbuf[W_NB + idx] = acc;
  }
  if (tid < NF * NC) {  // Wnf
    int r = tid >> 3, c = tid & 7;
    float acc = 0.f;
    for (int j = 0; j < HF; ++j)
      acc = fmaf(sW[LWn + r * HF + j], sW[LWfc + j * NC + c], acc);
    wbuf[W_NF + tid] = acc;
  }
  if (tid < EF) {  // bcomb
    float acc = sW[Lbem + tid];
    for (int j = 0; j < HF; ++j)
      acc = fmaf(sW[Lbe + j], sW[LWem + (HF + j) * EF + tid], acc);
    wbuf[B_COMB + tid] = acc;
  }
  if (tid < NF) {  // bvec
    float acc = 0.f;
    for (int j = 0; j < HF; ++j)
      acc = fmaf(sW[Lbe + j], sW[LWnm + j * NF + tid], acc);
    wbuf[B_VEC + tid] = acc;
  }
  if (tid < NF) {  // bSD
    float acc = 0.f;
    if (tid < EF) {
      for (int j = 0; j < HF; ++j)
        acc = fmaf(sW[Lbn + j], sW[LWem + j * EF + tid], acc);
    } else {
      int cc = tid - EF;
      for (int j = 0; j < HF; ++j)
        acc = fmaf(sW[Lbn + j], sW[LWem + (2 * HF + j) * EF + cc], acc);
    }
    wbuf[B_SD + tid] = acc;
  }
  if (tid < NF) {  // bNB
    float acc = sW[Lbnm + tid];
    for (int j = 0; j < HF; ++j)
      acc = fmaf(sW[Lbn + j], sW[LWnm + (HF + j) * NF + tid], acc);
    wbuf[B_NB + tid] = acc;
  }
  if (tid < NC) {  // bnf
    float acc = sW[Lbfc + tid];
    for (int j = 0; j < HF; ++j)
      acc = fmaf(sW[Lbn + j], sW[LWfc + j * NC + tid], acc);
    wbuf[B_NF + tid] = acc;
  }
}

// exclusive scan of cnt[30000] -> off[30001], cursor = copy of off
__global__ void __launch_bounds__(1024) scan_kernel(
    const int* __restrict__ cnt, int* __restrict__ off, int* __restrict__ cursor) {
  __shared__ int part[1024];
  int t = threadIdx.x;
  const int CH = (N_NODES + 1023) / 1024;   // 30
  int base = t * CH;
  int lc[CH];
  int sum = 0;
  for (int i = 0; i < CH; ++i) {
    int idx = base + i;
    lc[i] = (idx < N_NODES) ? cnt[idx] : 0;
    sum += lc[i];
  }
  part[t] = sum;
  __syncthreads();
  for (int ofs = 1; ofs < 1024; ofs <<= 1) {
    int v = (t >= ofs) ? part[t - ofs] : 0;
    __syncthreads();
    part[t] += v;
    __syncthreads();
  }
  int run = (t == 0) ? 0 : part[t - 1];
  for (int i = 0; i < CH; ++i) {
    int idx = base + i;
    if (idx < N_NODES) {
      off[idx] = run;
      cursor[idx] = run;
      run += lc[i];
    }
  }
  if (t == 1023) off[N_NODES] = part[1023];
}

// ---------------------------------------------------------------------------
// scatter (blocks 0..EB-1) + init_proj (blocks EB..EB+NB2-1).
// ---------------------------------------------------------------------------
__global__ void __launch_bounds__(256) scatter_init_kernel(
    const float* __restrict__ edge_feat, const int* __restrict__ src,
    const int* __restrict__ dst, int* __restrict__ cursor,
    unsigned short* __restrict__ src_s, unsigned short* __restrict__ dst_s,
    float* __restrict__ e_buf,
    const float* __restrict__ node_feat, const float* __restrict__ wbuf,
    float* __restrict__ Ps, float* __restrict__ Pd, float* __restrict__ hpart) {
  if (blockIdx.x < EB_GRID) {
    int e = blockIdx.x * 256 + threadIdx.x;
    if (e >= N_EDGES) return;
    int d = dst[e];
    int pos = atomicAdd(&cursor[d], 1);
    src_s[pos] = (unsigned short)src[e];
    dst_s[pos] = (unsigned short)d;
    const float4* ep = (const float4*)(edge_feat + (size_t)e * EF);
    float4* op = (float4*)(e_buf + (size_t)pos * EF);
    op[0] = ep[0]; op[1] = ep[1]; op[2] = ep[2]; op[3] = ep[3];
    return;
  }
  __shared__ float sPRJ[2048];
  __shared__ float sPB[64];
  for (int i = threadIdx.x; i < 2048; i += 256) sPRJ[i] = wbuf[W_SD + i];
  if (threadIdx.x < 64) sPB[threadIdx.x] = wbuf[B_SD + threadIdx.x];
  __syncthreads();
  int gid = (blockIdx.x - EB_GRID) * 256 + threadIdx.x;
  int n = gid >> 1, p = gid & 1;
  if (n >= N_NODES) return;
  float x[NF];
  const float4* xp = (const float4*)(node_feat + (size_t)n * NF);
#pragma unroll
  for (int k4 = 0; k4 < 8; ++k4) {
    float4 v = xp[k4];
    x[4 * k4] = v.x; x[4 * k4 + 1] = v.y; x[4 * k4 + 2] = v.z; x[4 * k4 + 3] = v.w;
  }
  float pr[NF];
  const float* pb = sPB + p * 32;
#pragma unroll
  for (int j = 0; j < NF; ++j) pr[j] = pb[j];
  const float* wbase = sPRJ + p * 1024;
  for (int k = 0; k < NF; ++k) {
    float v = x[k];
    const float4* wr = (const float4*)(wbase + k * NF);
#pragma unroll
    for (int j4 = 0; j4 < 8; ++j4) {
      float4 w = wr[j4];
      pr[4 * j4 + 0] = fmaf(v, w.x, pr[4 * j4 + 0]);
      pr[4 * j4 + 1] = fmaf(v, w.y, pr[4 * j4 + 1]);
      pr[4 * j4 + 2] = fmaf(v, w.z, pr[4 * j4 + 2]);
      pr[4 * j4 + 3] = fmaf(v, w.w, pr[4 * j4 + 3]);
    }
  }
  if (p == 0) {
    float4* a = (float4*)(Ps + (size_t)n * EF);
    a[0] = make_float4(pr[0], pr[1], pr[2], pr[3]);
    a[1] = make_float4(pr[4], pr[5], pr[6], pr[7]);
    a[2] = make_float4(pr[8], pr[9], pr[10], pr[11]);
    a[3] = make_float4(pr[12], pr[13], pr[14], pr[15]);
    float4* b = (float4*)(Pd + (size_t)n * EF);
    b[0] = make_float4(pr[16], pr[17], pr[18], pr[19]);
    b[1] = make_float4(pr[20], pr[21], pr[22], pr[23]);
    b[2] = make_float4(pr[24], pr[25], pr[26], pr[27]);
    b[3] = make_float4(pr[28], pr[29], pr[30], pr[31]);
  } else {
    float4* h = (float4*)(hpart + (size_t)n * NF);
#pragma unroll
    for (int j4 = 0; j4 < 8; ++j4)
      h[j4] = make_float4(pr[4 * j4], pr[4 * j4 + 1], pr[4 * j4 + 2], pr[4 * j4 + 3]);
  }
}

// ---------------------------------------------------------------------------
// conflict-free two-phase segment reduce over one 256-row half of sZ.
// Span [d_lo, d_hi) closes gaps: deg-0/gap nodes get plain-stored 0.
// atomicAdd only for nodes whose range crosses the half bounds (pre-zeroed
// by node side via crossF); atomicAdd(0) on unzeroed nodes is order-safe.
// ---------------------------------------------------------------------------
__device__ __forceinline__ void edge_reduce(
    const float* sZ, const int* __restrict__ off, float* __restrict__ aggW,
    int baseH, int endH, int d_lo, int d_hi, int t) {
  int f = (t & 7) * 2;
  for (int r = t >> 3; d_lo + r < d_hi; r += 32) {
    int dd = d_lo + r;
    int lo = off[dd], hi = off[dd + 1];
    int ql = lo > baseH ? lo : baseH;
    int qh = hi < endH ? hi : endH;
    float s0 = 0.f, s1 = 0.f;
    for (int qq = ql; qq < qh; ++qq) {
      const float* zr = sZ + (qq - baseH) * ZSTR + f;
      s0 += zr[0]; s1 += zr[1];
    }
    float* grow = aggW + (size_t)dd * EF + f;
    if (lo >= baseH && hi <= endH) { grow[0] = s0; grow[1] = s1; }
    else { atomicAdd(&grow[0], s0); atomicAdd(&grow[1], s1); }
  }
}

// edge math on register-resident e state; updates e in place, stages to sZ.
__device__ __forceinline__ void edge_phase_half(
    float (&e)[EF],
    const float* __restrict__ Ps_cur, const float* __restrict__ Pd_cur,
    const float* sWC, const float* sBC, float* sZ,
    int s_reg, int d_reg, int t, bool act) {
  if (!act) return;
  const float4* ps = (const float4*)(Ps_cur + (size_t)s_reg * EF);
  const float4* pd = (const float4*)(Pd_cur + (size_t)d_reg * EF);
  float z[EF];
#pragma unroll
  for (int i4 = 0; i4 < 4; ++i4) {
    float4 a = ps[i4], bb = pd[i4];
    z[4 * i4 + 0] = sBC[4 * i4 + 0] + a.x + bb.x;
    z[4 * i4 + 1] = sBC[4 * i4 + 1] + a.y + bb.y;
    z[4 * i4 + 2] = sBC[4 * i4 + 2] + a.z + bb.z;
    z[4 * i4 + 3] = sBC[4 * i4 + 3] + a.w + bb.w;
  }
#pragma unroll
  for (int k = 0; k < EF; ++k) {
    float v = e[k];
    const float4* wr = (const float4*)(sWC + k * EF);
#pragma unroll
    for (int i4 = 0; i4 < 4; ++i4) {
      float4 w = wr[i4];
      z[4 * i4 + 0] = fmaf(v, w.x, z[4 * i4 + 0]);
      z[4 * i4 + 1] = fmaf(v, w.y, z[4 * i4 + 1]);
      z[4 * i4 + 2] = fmaf(v, w.z, z[4 * i4 + 2]);
      z[4 * i4 + 3] = fmaf(v, w.w, z[4 * i4 + 3]);
    }
  }
  float* zr = sZ + t * ZSTR;
#pragma unroll
  for (int j = 0; j < EF; ++j) { e[j] = sigmoidf_(z[j]); zr[j] = e[j]; }
}

// ---------------------------------------------------------------------------
// Persistent kernel (plain launch + distributed store-slot barrier with
// replicated broadcast flags). 704 blocks: [0,235) node role (128 nodes,
// 2 thr/node; hpart in p1's registers, shfl-exchanged); [235,704) edge role
// (512 edges, 2/thread, e-state in registers all 12 phases).
// ---------------------------------------------------------------------------
__global__ void __launch_bounds__(256, 3) persist_kernel(
    const float* __restrict__ e_b0,
    const unsigned short* __restrict__ src_s, const unsigned short* __restrict__ dst_s,
    float* __restrict__ Ps0, float* __restrict__ Pd0,
    float* __restrict__ Ps1, float* __restrict__ Pd1,
    float* __restrict__ hpart, const int* __restrict__ off,
    const float* __restrict__ wbuf,
    float* __restrict__ G0, float* __restrict__ G1,
    float* __restrict__ out, int* __restrict__ bar) {
  __shared__ float smem[4640];   // node: 2920 used; edge: 272 + 4352 = 4624
  int t = threadIdx.x;
  int b = blockIdx.x;
  float* PsA[2] = {Ps0, Ps1};
  float* PdA[2] = {Pd0, Pd1};
  float* GAv[2] = {G0, G1};

  if (b < NODE_B) {
    // ================= NODE ROLE =================
    float* sNW = smem;  // sPRJ 2048 | sWnc 512 | sPB 64 | sbvec 32 | sWNF 256 | sBNF 8
    for (int i = t; i < 2048; i += 256) sNW[i] = wbuf[W_SD + i];
    for (int i = t; i < 512; i += 256) sNW[2048 + i] = wbuf[W_NC + i];
    if (t < 64) sNW[2560 + t] = wbuf[B_SD + t];
    if (t < 32) sNW[2624 + t] = wbuf[B_VEC + t];
    sNW[2656 + t] = wbuf[W_NF + t];
    if (t < 8) sNW[2912 + t] = wbuf[B_NF + t];
    __syncthreads();
    int n = b * 128 + (t >> 1), p = t & 1;
    bool actN = (n < N_NODES);
    float dg = 0.f;
    bool crossF = false;
    if (actN) {
      int o0 = off[n], o1 = off[n + 1];
      dg = (float)(o1 - o0);
      crossF = (o1 > o0) && ((o0 >> 8) != ((o1 - 1) >> 8));
    }
    // hpart in registers: p1 holds hv[32] (from scatter_init's write)
    float hv[NF];
#pragma unroll
    for (int j = 0; j < NF; ++j) hv[j] = 0.f;
    if (actN && p == 1) {
      const float4* hp = (const float4*)(hpart + (size_t)n * NF);
#pragma unroll
      for (int j4 = 0; j4 < 8; ++j4) {
        float4 v = hp[j4];
        hv[4 * j4] = v.x; hv[4 * j4 + 1] = v.y;
        hv[4 * j4 + 2] = v.z; hv[4 * j4 + 3] = v.w;
      }
    }

    gbarrier(bar, 1, false);   // phase 0: edge roles build G0

    for (int i = 1; i <= 11; ++i) {
      bool notlast = (i < 11);
      if (actN) {
        float* aggR = GAv[(i + 1) & 1];
        float* ar = aggR + (size_t)n * EF + 8 * p;
        float4 a0 = ((const float4*)ar)[0];
        float4 a1 = ((const float4*)ar)[1];
        if (notlast && crossF) {  // zero ONLY boundary-atomic targets
          ((float4*)ar)[0] = make_float4(0.f, 0.f, 0.f, 0.f);
          ((float4*)ar)[1] = make_float4(0.f, 0.f, 0.f, 0.f);
        }
        float s8[8] = {a0.x, a0.y, a0.z, a0.w, a1.x, a1.y, a1.z, a1.w};

        float z[NF];
#pragma unroll
        for (int j = 0; j < NF; ++j) {
          float hvv = __shfl_xor(hv[j], 1, 64);   // p0 <- p1's hpart
          z[j] = (p == 0) ? hvv : dg * sNW[2624 + j];
        }
#pragma unroll
        for (int k = 0; k < 8; ++k) {
          float v = s8[k];
          const float4* wr = (const float4*)(sNW + 2048 + (8 * p + k) * NF);
#pragma unroll
          for (int j4 = 0; j4 < 8; ++j4) {
            float4 w = wr[j4];
            z[4 * j4 + 0] = fmaf(v, w.x, z[4 * j4 + 0]);
            z[4 * j4 + 1] = fmaf(v, w.y, z[4 * j4 + 1]);
            z[4 * j4 + 2] = fmaf(v, w.z, z[4 * j4 + 2]);
            z[4 * j4 + 3] = fmaf(v, w.w, z[4 * j4 + 3]);
          }
        }
#pragma unroll
        for (int j = 0; j < NF; ++j) z[j] += __shfl_xor(z[j], 1, 64);
#pragma unroll
        for (int j = 0; j < NF; ++j) z[j] = sigmoidf_(z[j]);

        float pr[NF];
        const float* pb = sNW + 2560 + p * 32;
#pragma unroll
        for (int j = 0; j < NF; ++j) pr[j] = pb[j];
        const float* wbase = sNW + p * 1024;
        for (int k = 0; k < NF; ++k) {
          float v = z[k];
          const float4* wr = (const float4*)(wbase + k * NF);
#pragma unroll
          for (int j4 = 0; j4 < 8; ++j4) {
            float4 w = wr[j4];
            pr[4 * j4 + 0] = fmaf(v, w.x, pr[4 * j4 + 0]);
            pr[4 * j4 + 1] = fmaf(v, w.y, pr[4 * j4 + 1]);
            pr[4 * j4 + 2] = fmaf(v, w.z, pr[4 * j4 + 2]);
            pr[4 * j4 + 3] = fmaf(v, w.w, pr[4 * j4 + 3]);
          }
        }
        if (p == 0) {
          if (notlast) {   // pass-11 P writes dead (no edge pass 12)
            float* Ps_next = PsA[(i + 1) & 1];
            float* Pd_next = PdA[(i + 1) & 1];
            float4* a = (float4*)(Ps_next + (size_t)n * EF);
            a[0] = make_float4(pr[0], pr[1], pr[2], pr[3]);
            a[1] = make_float4(pr[4], pr[5], pr[6], pr[7]);
            a[2] = make_float4(pr[8], pr[9], pr[10], pr[11]);
            a[3] = make_float4(pr[12], pr[13], pr[14], pr[15]);
            float4* bb = (float4*)(Pd_next + (size_t)n * EF);
            bb[0] = make_float4(pr[16], pr[17], pr[18], pr[19]);
            bb[1] = make_float4(pr[20], pr[21], pr[22], pr[23]);
            bb[2] = make_float4(pr[24], pr[25], pr[26], pr[27]);
            bb[3] = make_float4(pr[28], pr[29], pr[30], pr[31]);
          }
        } else {
#pragma unroll
          for (int j = 0; j < NF; ++j) hv[j] = pr[j];   // hpart stays in regs
        }
      }
      gbarrier(bar, 1 + i, false);
    }

    // ---- final node pass (iter 12) + output head ----
    if (actN) {
      const float4* ap = (const float4*)(G1 + (size_t)n * EF + 8 * p);
      float4 a0 = ap[0], a1 = ap[1];
      float s8[8] = {a0.x, a0.y, a0.z, a0.w, a1.x, a1.y, a1.z, a1.w};
      float z[NF];
#pragma unroll
      for (int j = 0; j < NF; ++j) {
        float hvv = __shfl_xor(hv[j], 1, 64);
        z[j] = (p == 0) ? hvv : dg * sNW[2624 + j];
      }
#pragma unroll
      for (int k = 0; k < 8; ++k) {
        float v = s8[k];
        const float4* wr = (const float4*)(sNW + 2048 + (8 * p + k) * NF);
#pragma unroll
        for (int j4 = 0; j4 < 8; ++j4) {
          float4 w = wr[j4];
          z[4 * j4 + 0] = fmaf(v, w.x, z[4 * j4 + 0]);
          z[4 * j4 + 1] = fmaf(v, w.y, z[4 * j4 + 1]);
          z[4 * j4 + 2] = fmaf(v, w.z, z[4 * j4 + 2]);
          z[4 * j4 + 3] = fmaf(v, w.w, z[4 * j4 + 3]);
        }
      }
#pragma unroll
      for (int j = 0; j < NF; ++j) z[j] += __shfl_xor(z[j], 1, 64);
#pragma unroll
      for (int j = 0; j < NF; ++j) z[j] = sigmoidf_(z[j]);

      float o[NC];
      float pm = (p == 0) ? 1.0f : 0.0f;
#pragma unroll
      for (int c = 0; c < NC; ++c) o[c] = pm * sNW[2912 + c];
      for (int k = 0; k < 16; ++k) {
        float v = z[16 * p + k];
        const float* wr = sNW + 2656 + (16 * p + k) * NC;
#pragma unroll
        for (int c = 0; c < NC; ++c) o[c] = fmaf(v, wr[c], o[c]);
      }
#pragma unroll
      for (int c = 0; c < NC; ++c) o[c] += __shfl_xor(o[c], 1, 64);
      if (p == 0) {
        float4* op = (float4*)(out + (size_t)n * NC);
        op[0] = make_float4(o[0], o[1], o[2], o[3]);
        op[1] = make_float4(o[4], o[5], o[6], o[7]);
      }
    }
  } else {
    // ================= EDGE ROLE (e-state in registers) =================
    float* sWC = smem;          // 256
    float* sBC = smem + 256;    // 16
    float* sZ  = smem + 272;    // 256*17 = 4352
    sWC[t] = wbuf[W_COMB + t];
    if (t < EF) sBC[t] = wbuf[B_COMB + t];

    int c = b - NODE_B;
    int base = c * 512;
    int end = base + 512; if (end > N_EDGES) end = N_EDGES;
    int cnt = end - base;
    int h1n = cnt - 256;
    int q0 = base + t;
    int q1 = base + 256 + t;
    bool act1 = (t < h1n);
    int s0 = src_s[q0], d0 = dst_s[q0];
    int s1 = 0, d1 = 0;
    if (act1) { s1 = src_s[q1]; d1 = dst_s[q1]; }
    // gap-closing spans: half0 covers [df0 (or 0), df1]; half1 covers
    // [df1, next chunk's first dst] (or N_NODES for the last chunk).
    int df0 = dst_s[base];
    int df1 = dst_s[base + 256];
    int dlo0 = (c == 0) ? 0 : df0;
    int dhi0 = df1 + 1;
    int dlo1 = df1;
    int dhi1 = (c + 1 < EDGE_B) ? ((int)dst_s[(c + 1) * 512] + 1) : N_NODES;

    // load e-state into registers (ONLY global e access in the kernel)
    float e0[EF], e1[EF];
    {
      const float4* p4 = (const float4*)(e_b0 + (size_t)q0 * EF);
      float4 v0 = p4[0], v1 = p4[1], v2 = p4[2], v3 = p4[3];
      e0[0]=v0.x; e0[1]=v0.y; e0[2]=v0.z; e0[3]=v0.w;
      e0[4]=v1.x; e0[5]=v1.y; e0[6]=v1.z; e0[7]=v1.w;
      e0[8]=v2.x; e0[9]=v2.y; e0[10]=v2.z; e0[11]=v2.w;
      e0[12]=v3.x; e0[13]=v3.y; e0[14]=v3.z; e0[15]=v3.w;
    }
    if (act1) {
      const float4* p4 = (const float4*)(e_b0 + (size_t)q1 * EF);
      float4 v0 = p4[0], v1 = p4[1], v2 = p4[2], v3 = p4[3];
      e1[0]=v0.x; e1[1]=v0.y; e1[2]=v0.z; e1[3]=v0.w;
      e1[4]=v1.x; e1[5]=v1.y; e1[6]=v1.z; e1[7]=v1.w;
      e1[8]=v2.x; e1[9]=v2.y; e1[10]=v2.z; e1[11]=v2.w;
      e1[12]=v3.x; e1[13]=v3.y; e1[14]=v3.z; e1[15]=v3.w;
    } else {
#pragma unroll
      for (int j = 0; j < EF; ++j) e1[j] = 0.f;
    }
    __syncthreads();

    // ---- phase 0: G0 = segsum(raw e) ----
    {
      float* zr = sZ + t * ZSTR;
#pragma unroll
      for (int j = 0; j < EF; ++j) zr[j] = e0[j];
      __syncthreads();
      edge_reduce(sZ, off, G0, base, base + 256, dlo0, dhi0, t);
      __syncthreads();
      if (act1) {
#pragma unroll
        for (int j = 0; j < EF; ++j) zr[j] = e1[j];
      }
      __syncthreads();
      edge_reduce(sZ, off, G0, base + 256, end, dlo1, dhi1, t);
    }
    gbarrier(bar, 1, false);

    // ---- 11 edge passes ----
    for (int i = 1; i <= 11; ++i) {
      const float* Ps_cur = PsA[i & 1];
      const float* Pd_cur = PdA[i & 1];
      float* aggW = GAv[i & 1];
      edge_phase_half(e0, Ps_cur, Pd_cur, sWC, sBC, sZ, s0, d0, t, true);
      __syncthreads();
      edge_reduce(sZ, off, aggW, base, base + 256, dlo0, dhi0, t);
      __syncthreads();
      edge_phase_half(e1, Ps_cur, Pd_cur, sWC, sBC, sZ, s1, d1, t, act1);
      __syncthreads();
      edge_reduce(sZ, off, aggW, base + 256, end, dlo1, dhi1, t);
      gbarrier(bar, 1 + i, i == 11);   // last: signal and exit (no wait)
    }
  }
}

// ---------------------------------------------------------------------------
extern "C" void kernel_launch(void* const* d_in, const int* in_sizes, int n_in,
                              void* d_out, int out_size, void* d_ws, size_t ws_size,
                              hipStream_t stream) {
  const float* node_feat = (const float*)d_in[0];
  const float* edge_feat = (const float*)d_in[1];
  const int*   src = (const int*)d_in[2];
  const int*   dst = (const int*)d_in[3];
  const float* Wn  = (const float*)d_in[4];
  const float* bn  = (const float*)d_in[5];
  const float* We  = (const float*)d_in[6];
  const float* be  = (const float*)d_in[7];
  const float* Wem = (const float*)d_in[8];
  const float* bem = (const float*)d_in[9];
  const float* Wnm = (const float*)d_in[10];
  const float* bnm = (const float*)d_in[11];
  const float* Wfc = (const float*)d_in[12];
  const float* bfc = (const float*)d_in[13];
  float* out = (float*)d_out;

  float* ws    = (float*)d_ws;
  float* e_b0  = ws;                                   // 3,840,000 f
  float* e_b1  = e_b0 + (size_t)N_EDGES * EF;          // (unused; layout kept)
  float* hpart = e_b1 + (size_t)N_EDGES * EF;          //   960,000 f
  float* Ps0   = hpart + (size_t)N_NODES * NF;         //   480,000 f
  float* Pd0   = Ps0 + (size_t)N_NODES * EF;
  float* Ps1   = Pd0 + (size_t)N_NODES * EF;
  float* Pd1   = Ps1 + (size_t)N_NODES * EF;
  float* G0    = Pd1 + (size_t)N_NODES * EF;           //   480,000 f
  float* G1    = G0 + (size_t)N_NODES * EF;            //   480,000 f
  float* wbuf  = G1 + (size_t)N_NODES * EF;            //     4,096 f
  int* cnt     = (int*)(wbuf + 4096);                  //    30,000 i
  int* off     = cnt + N_NODES;                        //    30,001 i
  int* cursor  = off + N_NODES + 1;                    //    30,000 i
  unsigned short* src_s = (unsigned short*)(cursor + N_NODES);  // 240,000 u16
  unsigned short* dst_s = src_s + N_EDGES;                      // 240,000 u16
  int* bar     = (int*)(dst_s + N_EDGES);              // BAR_INTS ints

  // --- preamble: counting sort + weight folding; zero agg buffers ---
  hipMemsetAsync(cnt, 0, (size_t)N_NODES * sizeof(int), stream);
  hipMemsetAsync(G0, 0, (size_t)2 * N_NODES * EF * sizeof(float), stream);
  hist_pre_kernel<<<EB_GRID + 1, 256, 0, stream>>>(
      dst, cnt, Wn, bn, We, be, Wem, bem, Wnm, bnm, Wfc, bfc, wbuf, bar);
  scan_kernel<<<1, 1024, 0, stream>>>(cnt, off, cursor);
  scatter_init_kernel<<<EB_GRID + NB2_GRID, 256, 0, stream>>>(
      edge_feat, src, dst, cursor, src_s, dst_s, e_b0,
      node_feat, wbuf, Ps1, Pd1, hpart);

  // --- persistent kernel: prologue-agg + 11 fused passes + final ---
  persist_kernel<<<NBLK_P, 256, 0, stream>>>(
      e_b0, src_s, dst_s, Ps0, Pd0, Ps1, Pd1,
      hpart, off, wbuf, G0, G1, out, bar);
}

// Round 11
// 429.539 us; speedup vs baseline: 6.3397x; 1.4801x over previous
//
#include <hip/hip_runtime.h>

#define N_NODES 30000
#define N_EDGES 240000
#define NF 32
#define EF 16
#define HF 64
#define NC 8

#define EB_GRID  938   // (N_EDGES + 255) / 256
#define NB2_GRID 235   // (2*N_NODES + 255) / 256
#define ZSTR     17    // sZ row stride (odd -> free 2-way bank aliasing)

// wbuf layout (float offsets)
#define W_COMB 0      // [16][16] We @ Wem[64:128)
#define B_COMB 256    // [16]     bem + be@Wem[64:128)
#define W_NC   272    // [16][32] We @ Wnm[0:64)
#define B_VEC  784    // [32]     be @ Wnm[0:64)
#define W_SD   816    // [32][32] cols 0-15: Wn@Wem[0:64) ; 16-31: Wn@Wem[128:192)
#define W_NB   1840   // [32][32] Wn @ Wnm[64:128)
#define B_SD   2864   // [32]     [bn@WemS | bn@WemD]
#define B_NB   2896   // [32]     bnm + bn@Wnm[64:128)
#define W_NF   2928   // [32][8]  Wn @ Wfc
#define B_NF   3184   // [8]      bfc + bn@Wfc

// precompute LDS staging layout (float offsets)
#define LWn   0
#define LWe   2048
#define LWem  3072
#define LWnm  6144
#define LWfc  10240
#define Lbn   10752
#define Lbe   10816
#define Lbem  10880
#define Lbnm  10896
#define Lbfc  10928
#define LTOT  10936

__device__ __forceinline__ float sigmoidf_(float x) {
  return 1.0f / (1.0f + __expf(-x));
}

// ---------------------------------------------------------------------------
// hist (blocks 0..EB-1) + precompute (block EB) — LDS-staged weight folding.
// ---------------------------------------------------------------------------
__global__ void __launch_bounds__(256) hist_pre_kernel(
    const int* __restrict__ dst, int* __restrict__ cnt,
    const float* __restrict__ Wn, const float* __restrict__ bn,
    const float* __restrict__ We, const float* __restrict__ be,
    const float* __restrict__ Wem, const float* __restrict__ bem,
    const float* __restrict__ Wnm, const float* __restrict__ bnm,
    const float* __restrict__ Wfc, const float* __restrict__ bfc,
    float* __restrict__ wbuf) {
  __shared__ float sW[LTOT];
  if (blockIdx.x < EB_GRID) {
    int e = blockIdx.x * 256 + threadIdx.x;
    if (e < N_EDGES) atomicAdd(&cnt[dst[e]], 1);
    return;
  }
  int tid = threadIdx.x;
  for (int i = tid; i < 2048; i += 256) sW[LWn + i] = Wn[i];
  for (int i = tid; i < 1024; i += 256) sW[LWe + i] = We[i];
  for (int i = tid; i < 3072; i += 256) sW[LWem + i] = Wem[i];
  for (int i = tid; i < 4096; i += 256) sW[LWnm + i] = Wnm[i];
  for (int i = tid; i < 512; i += 256) sW[LWfc + i] = Wfc[i];
  if (tid < 64) sW[Lbn + tid] = bn[tid];
  if (tid < 64) sW[Lbe + tid] = be[tid];
  if (tid < 16) sW[Lbem + tid] = bem[tid];
  if (tid < 32) sW[Lbnm + tid] = bnm[tid];
  if (tid < 8)  sW[Lbfc + tid] = bfc[tid];
  __syncthreads();
  {  // Wcomb
    int r = tid >> 4, c = tid & 15;
    float acc = 0.f;
    for (int j = 0; j < HF; ++j)
      acc = fmaf(sW[LWe + r * HF + j], sW[LWem + (HF + j) * EF + c], acc);
    wbuf[W_COMB + tid] = acc;
  }
  for (int idx = tid; idx < EF * NF; idx += 256) {  // Wnc
    int r = idx >> 5, c = idx & 31;
    float acc = 0.f;
    for (int j = 0; j < HF; ++j)
      acc = fmaf(sW[LWe + r * HF + j], sW[LWnm + j * NF + c], acc);
    wbuf[W_NC + idx] = acc;
  }
  for (int idx = tid; idx < NF * NF; idx += 256) {  // WSD
    int r = idx >> 5, c = idx & 31;
    float acc = 0.f;
    if (c < EF) {
      for (int j = 0; j < HF; ++j)
        acc = fmaf(sW[LWn + r * HF + j], sW[LWem + j * EF + c], acc);
    } else {
      int cc = c - EF;
      for (int j = 0; j < HF; ++j)
        acc = fmaf(sW[LWn + r * HF + j], sW[LWem + (2 * HF + j) * EF + cc], acc);
    }
    wbuf[W_SD + idx] = acc;
  }
  for (int idx = tid; idx < NF * NF; idx += 256) {  // WnB
    int r = idx >> 5, c = idx & 31;
    float acc = 0.f;
    for (int j = 0; j < HF; ++j)
      acc = fmaf(sW[LWn + r * HF + j], sW[LWnm + (HF + j) * NF + c], acc);
    wbuf[W_NB + idx] = acc;
  }
  if (tid < NF * NC) {  // Wnf
    int r = tid >> 3, c = tid & 7;
    float acc = 0.f;
    for (int j = 0; j < HF; ++j)
      acc = fmaf(sW[LWn + r * HF + j], sW[LWfc + j * NC + c], acc);
    wbuf[W_NF + tid] = acc;
  }
  if (tid < EF) {  // bcomb
    float acc = sW[Lbem + tid];
    for (int j = 0; j < HF; ++j)
      acc = fmaf(sW[Lbe + j], sW[LWem + (HF + j) * EF + tid], acc);
    wbuf[B_COMB + tid] = acc;
  }
  if (tid < NF) {  // bvec
    float acc = 0.f;
    for (int j = 0; j < HF; ++j)
      acc = fmaf(sW[Lbe + j], sW[LWnm + j * NF + tid], acc);
    wbuf[B_VEC + tid] = acc;
  }
  if (tid < NF) {  // bSD
    float acc = 0.f;
    if (tid < EF) {
      for (int j = 0; j < HF; ++j)
        acc = fmaf(sW[Lbn + j], sW[LWem + j * EF + tid], acc);
    } else {
      int cc = tid - EF;
      for (int j = 0; j < HF; ++j)
        acc = fmaf(sW[Lbn + j], sW[LWem + (2 * HF + j) * EF + cc], acc);
    }
    wbuf[B_SD + tid] = acc;
  }
  if (tid < NF) {  // bNB
    float acc = sW[Lbnm + tid];
    for (int j = 0; j < HF; ++j)
      acc = fmaf(sW[Lbn + j], sW[LWnm + (HF + j) * NF + tid], acc);
    wbuf[B_NB + tid] = acc;
  }
  if (tid < NC) {  // bnf
    float acc = sW[Lbfc + tid];
    for (int j = 0; j < HF; ++j)
      acc = fmaf(sW[Lbn + j], sW[LWfc + j * NC + tid], acc);
    wbuf[B_NF + tid] = acc;
  }
}

// exclusive scan of cnt[30000] -> off[30001], cursor = copy of off
__global__ void __launch_bounds__(1024) scan_kernel(
    const int* __restrict__ cnt, int* __restrict__ off, int* __restrict__ cursor) {
  __shared__ int part[1024];
  int t = threadIdx.x;
  const int CH = (N_NODES + 1023) / 1024;   // 30
  int base = t * CH;
  int lc[CH];
  int sum = 0;
  for (int i = 0; i < CH; ++i) {
    int idx = base + i;
    lc[i] = (idx < N_NODES) ? cnt[idx] : 0;
    sum += lc[i];
  }
  part[t] = sum;
  __syncthreads();
  for (int ofs = 1; ofs < 1024; ofs <<= 1) {
    int v = (t >= ofs) ? part[t - ofs] : 0;
    __syncthreads();
    part[t] += v;
    __syncthreads();
  }
  int run = (t == 0) ? 0 : part[t - 1];
  for (int i = 0; i < CH; ++i) {
    int idx = base + i;
    if (idx < N_NODES) {
      off[idx] = run;
      cursor[idx] = run;
      run += lc[i];
    }
  }
  if (t == 1023) off[N_NODES] = part[1023];
}

// ---------------------------------------------------------------------------
// scatter (blocks 0..EB-1) + init_proj (blocks EB..EB+NB2-1).
// ---------------------------------------------------------------------------
__global__ void __launch_bounds__(256) scatter_init_kernel(
    const float* __restrict__ edge_feat, const int* __restrict__ src,
    const int* __restrict__ dst, int* __restrict__ cursor,
    unsigned short* __restrict__ src_s, unsigned short* __restrict__ dst_s,
    float* __restrict__ e_buf,
    const float* __restrict__ node_feat, const float* __restrict__ wbuf,
    float* __restrict__ Ps, float* __restrict__ Pd, float* __restrict__ hpart) {
  if (blockIdx.x < EB_GRID) {
    int e = blockIdx.x * 256 + threadIdx.x;
    if (e >= N_EDGES) return;
    int d = dst[e];
    int pos = atomicAdd(&cursor[d], 1);
    src_s[pos] = (unsigned short)src[e];
    dst_s[pos] = (unsigned short)d;
    const float4* ep = (const float4*)(edge_feat + (size_t)e * EF);
    float4* op = (float4*)(e_buf + (size_t)pos * EF);
    op[0] = ep[0]; op[1] = ep[1]; op[2] = ep[2]; op[3] = ep[3];
    return;
  }
  __shared__ float sPRJ[2048];
  __shared__ float sPB[64];
  for (int i = threadIdx.x; i < 2048; i += 256) sPRJ[i] = wbuf[W_SD + i];
  if (threadIdx.x < 64) sPB[threadIdx.x] = wbuf[B_SD + threadIdx.x];
  __syncthreads();
  int gid = (blockIdx.x - EB_GRID) * 256 + threadIdx.x;
  int n = gid >> 1, p = gid & 1;
  if (n >= N_NODES) return;
  float x[NF];
  const float4* xp = (const float4*)(node_feat + (size_t)n * NF);
#pragma unroll
  for (int k4 = 0; k4 < 8; ++k4) {
    float4 v = xp[k4];
    x[4 * k4] = v.x; x[4 * k4 + 1] = v.y; x[4 * k4 + 2] = v.z; x[4 * k4 + 3] = v.w;
  }
  float pr[NF];
  const float* pb = sPB + p * 32;
#pragma unroll
  for (int j = 0; j < NF; ++j) pr[j] = pb[j];
  const float* wbase = sPRJ + p * 1024;
  for (int k = 0; k < NF; ++k) {
    float v = x[k];
    const float4* wr = (const float4*)(wbase + k * NF);
#pragma unroll
    for (int j4 = 0; j4 < 8; ++j4) {
      float4 w = wr[j4];
      pr[4 * j4 + 0] = fmaf(v, w.x, pr[4 * j4 + 0]);
      pr[4 * j4 + 1] = fmaf(v, w.y, pr[4 * j4 + 1]);
      pr[4 * j4 + 2] = fmaf(v, w.z, pr[4 * j4 + 2]);
      pr[4 * j4 + 3] = fmaf(v, w.w, pr[4 * j4 + 3]);
    }
  }
  if (p == 0) {
    float4* a = (float4*)(Ps + (size_t)n * EF);
    a[0] = make_float4(pr[0], pr[1], pr[2], pr[3]);
    a[1] = make_float4(pr[4], pr[5], pr[6], pr[7]);
    a[2] = make_float4(pr[8], pr[9], pr[10], pr[11]);
    a[3] = make_float4(pr[12], pr[13], pr[14], pr[15]);
    float4* b = (float4*)(Pd + (size_t)n * EF);
    b[0] = make_float4(pr[16], pr[17], pr[18], pr[19]);
    b[1] = make_float4(pr[20], pr[21], pr[22], pr[23]);
    b[2] = make_float4(pr[24], pr[25], pr[26], pr[27]);
    b[3] = make_float4(pr[28], pr[29], pr[30], pr[31]);
  } else {
    float4* h = (float4*)(hpart + (size_t)n * NF);
#pragma unroll
    for (int j4 = 0; j4 < 8; ++j4)
      h[j4] = make_float4(pr[4 * j4], pr[4 * j4 + 1], pr[4 * j4 + 2], pr[4 * j4 + 3]);
  }
}

// ---------------------------------------------------------------------------
// one-time agg0 = segsum(initial sorted e rows); 2 threads/node, unrolled x2.
// ---------------------------------------------------------------------------
__global__ void __launch_bounds__(256) agg0_kernel(
    const float* __restrict__ e_buf, const int* __restrict__ off,
    float* __restrict__ agg0) {
  int gid = blockIdx.x * 256 + threadIdx.x;
  int n = gid >> 1, p = gid & 1;
  if (n >= N_NODES) return;
  int o0 = off[n], o1 = off[n + 1];
  float4 sA = make_float4(0.f, 0.f, 0.f, 0.f);
  float4 sB = make_float4(0.f, 0.f, 0.f, 0.f);
  const float* ebase = e_buf + 8 * p;
  int q = o0;
  for (; q + 1 < o1; q += 2) {
    const float4* e0 = (const float4*)(ebase + (size_t)q * EF);
    const float4* e1 = (const float4*)(ebase + (size_t)(q + 1) * EF);
    float4 a = e0[0], b = e0[1], c = e1[0], d = e1[1];
    sA.x += a.x; sA.y += a.y; sA.z += a.z; sA.w += a.w;
    sB.x += b.x; sB.y += b.y; sB.z += b.z; sB.w += b.w;
    sA.x += c.x; sA.y += c.y; sA.z += c.z; sA.w += c.w;
    sB.x += d.x; sB.y += d.y; sB.z += d.z; sB.w += d.w;
  }
  if (q < o1) {
    const float4* e0 = (const float4*)(ebase + (size_t)q * EF);
    float4 a = e0[0], b = e0[1];
    sA.x += a.x; sA.y += a.y; sA.z += a.z; sA.w += a.w;
    sB.x += b.x; sB.y += b.y; sB.z += b.z; sB.w += b.w;
  }
  float4* ap = (float4*)(agg0 + (size_t)n * EF + 8 * p);
  ap[0] = sA; ap[1] = sB;
}

// ---------------------------------------------------------------------------
// fused pass i: node blocks [0, NB2) + edge blocks [NB2, NB2+EB).
// Identical dataflow to the verified 425us round-5 kernel, with two fixes:
// 1) LDS UNION: node/edge role layouts share one smem[4640] array
//    (round-5 summed both statically: ~29KB -> 5 blocks/CU; now 18.5KB ->
//    8 blocks/CU = 2x resident waves for this latency-bound kernel).
// 2) Dead-store elimination on pass 11 (notlast=0): e_dst write and P
//    writes are dead (final pass reads only G1 + hpart).
// ---------------------------------------------------------------------------
__global__ void __launch_bounds__(256) fused4_kernel(
    const float* __restrict__ e_src, float* __restrict__ e_dst,
    const unsigned short* __restrict__ src_s, const unsigned short* __restrict__ dst_s,
    const float* __restrict__ Ps_cur, const float* __restrict__ Pd_cur,
    float* __restrict__ hpart, const int* __restrict__ off,
    const float* __restrict__ wbuf,
    float* __restrict__ Ps_next, float* __restrict__ Pd_next,
    float* __restrict__ aggR, float* __restrict__ aggW, int notlast) {
  __shared__ float smem[4640];   // edge: 4626 used | node: 2656 used
  int t = threadIdx.x;
  if (blockIdx.x >= NB2_GRID) {
    // ---------------- edge body ----------------
    float* sWC = smem;            // 256
    float* sBC = smem + 256;      // 16
    float* sZ  = smem + 272;      // 4352
    int* sInfo = (int*)(smem + 4624);
    int b = blockIdx.x - NB2_GRID;
    int base = b * 256;
    int end = base + 256; if (end > N_EDGES) end = N_EDGES;
    sWC[t] = wbuf[W_COMB + t];
    if (t < EF) sBC[t] = wbuf[B_COMB + t];
    if (t == 0) { sInfo[0] = dst_s[base]; sInfo[1] = dst_s[end - 1]; }
    __syncthreads();
    int q = base + t;
    if (q < end) {
      int s = src_s[q], d = dst_s[q];
      float e[EF];
      const float4* ebp = (const float4*)(e_src + (size_t)q * EF);
#pragma unroll
      for (int k4 = 0; k4 < 4; ++k4) {
        float4 v = ebp[k4];
        e[4 * k4] = v.x; e[4 * k4 + 1] = v.y; e[4 * k4 + 2] = v.z; e[4 * k4 + 3] = v.w;
      }
      const float4* ps = (const float4*)(Ps_cur + (size_t)s * EF);
      const float4* pd = (const float4*)(Pd_cur + (size_t)d * EF);
      float z[EF];
#pragma unroll
      for (int i4 = 0; i4 < 4; ++i4) {
        float4 a = ps[i4], bb = pd[i4];
        z[4 * i4 + 0] = sBC[4 * i4 + 0] + a.x + bb.x;
        z[4 * i4 + 1] = sBC[4 * i4 + 1] + a.y + bb.y;
        z[4 * i4 + 2] = sBC[4 * i4 + 2] + a.z + bb.z;
        z[4 * i4 + 3] = sBC[4 * i4 + 3] + a.w + bb.w;
      }
#pragma unroll
      for (int k = 0; k < EF; ++k) {
        float v = e[k];
        const float4* wr = (const float4*)(sWC + k * EF);
#pragma unroll
        for (int i4 = 0; i4 < 4; ++i4) {
          float4 w = wr[i4];
          z[4 * i4 + 0] = fmaf(v, w.x, z[4 * i4 + 0]);
          z[4 * i4 + 1] = fmaf(v, w.y, z[4 * i4 + 1]);
          z[4 * i4 + 2] = fmaf(v, w.z, z[4 * i4 + 2]);
          z[4 * i4 + 3] = fmaf(v, w.w, z[4 * i4 + 3]);
        }
      }
#pragma unroll
      for (int i = 0; i < EF; ++i) z[i] = sigmoidf_(z[i]);
      if (notlast) {
        float4* obp = (float4*)(e_dst + (size_t)q * EF);
#pragma unroll
        for (int i4 = 0; i4 < 4; ++i4)
          obp[i4] = make_float4(z[4 * i4], z[4 * i4 + 1], z[4 * i4 + 2], z[4 * i4 + 3]);
      }
      float* zr = sZ + t * ZSTR;
#pragma unroll
      for (int j = 0; j < EF; ++j) zr[j] = z[j];
    }
    __syncthreads();
    // conflict-free segment reduction: node r = t>>3, features f, f+1
    int d_first = sInfo[0];
    int span = sInfo[1] - d_first + 1;
    int f = (t & 7) * 2;
    for (int r = t >> 3; r < span; r += 32) {
      int dd = d_first + r;
      int lo = off[dd], hi = off[dd + 1];
      int ql = lo > base ? lo : base;
      int qh = hi < end ? hi : end;
      float s0 = 0.f, s1 = 0.f;
      for (int qq = ql; qq < qh; ++qq) {
        const float* zr = sZ + (qq - base) * ZSTR + f;
        s0 += zr[0]; s1 += zr[1];
      }
      float* grow = aggW + (size_t)dd * EF + f;
      if (lo >= base && hi <= end) {
        grow[0] = s0; grow[1] = s1;
      } else {
        atomicAdd(&grow[0], s0);
        atomicAdd(&grow[1], s1);
      }
    }
    return;
  }
  // ---------------- node body (2 threads/node, agg-fed) ----------------
  float* sWnc  = smem;           // 512
  float* sbvec = smem + 512;     // 32
  float* sPRJ  = smem + 544;     // 2048
  float* sPB   = smem + 2592;    // 64
  for (int i = t; i < 2048; i += 256) sPRJ[i] = wbuf[W_SD + i];
  for (int i = t; i < EF * NF; i += 256) sWnc[i] = wbuf[W_NC + i];
  if (t < 64) sPB[t] = wbuf[B_SD + t];
  if (t < NF) sbvec[t] = wbuf[B_VEC + t];
  __syncthreads();
  int gid = blockIdx.x * 256 + t;
  int n = gid >> 1, p = gid & 1;
  if (n >= N_NODES) return;
  int o0 = off[n], o1 = off[n + 1];

  float* ar = aggR + (size_t)n * EF + 8 * p;
  float4 a0 = ((const float4*)ar)[0];
  float4 a1 = ((const float4*)ar)[1];
  if (notlast) {   // zero for edge_{i+1}; dead after pass 11
    ((float4*)ar)[0] = make_float4(0.f, 0.f, 0.f, 0.f);
    ((float4*)ar)[1] = make_float4(0.f, 0.f, 0.f, 0.f);
  }
  float s8[8] = {a0.x, a0.y, a0.z, a0.w, a1.x, a1.y, a1.z, a1.w};

  float z[NF];
  if (p == 0) {
    const float4* hp = (const float4*)(hpart + (size_t)n * NF);
#pragma unroll
    for (int j4 = 0; j4 < 8; ++j4) {
      float4 v = hp[j4];
      z[4 * j4] = v.x; z[4 * j4 + 1] = v.y; z[4 * j4 + 2] = v.z; z[4 * j4 + 3] = v.w;
    }
  } else {
    float dg = (float)(o1 - o0);
#pragma unroll
    for (int j = 0; j < NF; ++j) z[j] = dg * sbvec[j];
  }
#pragma unroll
  for (int k = 0; k < 8; ++k) {
    float v = s8[k];
    const float4* wr = (const float4*)(sWnc + (8 * p + k) * NF);
#pragma unroll
    for (int j4 = 0; j4 < 8; ++j4) {
      float4 w = wr[j4];
      z[4 * j4 + 0] = fmaf(v, w.x, z[4 * j4 + 0]);
      z[4 * j4 + 1] = fmaf(v, w.y, z[4 * j4 + 1]);
      z[4 * j4 + 2] = fmaf(v, w.z, z[4 * j4 + 2]);
      z[4 * j4 + 3] = fmaf(v, w.w, z[4 * j4 + 3]);
    }
  }
#pragma unroll
  for (int j = 0; j < NF; ++j) z[j] += __shfl_xor(z[j], 1, 64);
#pragma unroll
  for (int j = 0; j < NF; ++j) z[j] = sigmoidf_(z[j]);

  float pr[NF];
  const float* pb = sPB + p * 32;
#pragma unroll
  for (int j = 0; j < NF; ++j) pr[j] = pb[j];
  const float* wbase = sPRJ + p * 1024;
  for (int k = 0; k < NF; ++k) {
    float v = z[k];
    const float4* wr = (const float4*)(wbase + k * NF);
#pragma unroll
    for (int j4 = 0; j4 < 8; ++j4) {
      float4 w = wr[j4];
      pr[4 * j4 + 0] = fmaf(v, w.x, pr[4 * j4 + 0]);
      pr[4 * j4 + 1] = fmaf(v, w.y, pr[4 * j4 + 1]);
      pr[4 * j4 + 2] = fmaf(v, w.z, pr[4 * j4 + 2]);
      pr[4 * j4 + 3] = fmaf(v, w.w, pr[4 * j4 + 3]);
    }
  }
  if (p == 0) {
    if (notlast) {   // pass-11 P writes are dead (no edge pass 12)
      float4* a = (float4*)(Ps_next + (size_t)n * EF);
      a[0] = make_float4(pr[0], pr[1], pr[2], pr[3]);
      a[1] = make_float4(pr[4], pr[5], pr[6], pr[7]);
      a[2] = make_float4(pr[8], pr[9], pr[10], pr[11]);
      a[3] = make_float4(pr[12], pr[13], pr[14], pr[15]);
      float4* b = (float4*)(Pd_next + (size_t)n * EF);
      b[0] = make_float4(pr[16], pr[17], pr[18], pr[19]);
      b[1] = make_float4(pr[20], pr[21], pr[22], pr[23]);
      b[2] = make_float4(pr[24], pr[25], pr[26], pr[27]);
      b[3] = make_float4(pr[28], pr[29], pr[30], pr[31]);
    }
  } else {
    float4* h = (float4*)(hpart + (size_t)n * NF);
#pragma unroll
    for (int j4 = 0; j4 < 8; ++j4)
      h[j4] = make_float4(pr[4 * j4], pr[4 * j4 + 1], pr[4 * j4 + 2], pr[4 * j4 + 3]);
  }
}

// ---------------------------------------------------------------------------
// final node pass (iter 12), agg-fed: z/sig as above, then out = sig@Wnf+bnf
// ---------------------------------------------------------------------------
__global__ void __launch_bounds__(256) final_kernel(
    const float* __restrict__ aggR, const float* __restrict__ hpart,
    const int* __restrict__ off, const float* __restrict__ wbuf,
    float* __restrict__ out) {
  __shared__ float sWnc[EF * NF];
  __shared__ float sbvec[NF];
  __shared__ float sWNF[NF * NC];
  __shared__ float sBNF[NC];
  for (int i = threadIdx.x; i < EF * NF; i += 256) sWnc[i] = wbuf[W_NC + i];
  if (threadIdx.x < NF) sbvec[threadIdx.x] = wbuf[B_VEC + threadIdx.x];
  if (threadIdx.x < NF * NC) sWNF[threadIdx.x] = wbuf[W_NF + threadIdx.x];
  if (threadIdx.x < NC) sBNF[threadIdx.x] = wbuf[B_NF + threadIdx.x];
  __syncthreads();
  int gid = blockIdx.x * 256 + threadIdx.x;
  int n = gid >> 1, p = gid & 1;
  if (n >= N_NODES) return;
  int o0 = off[n], o1 = off[n + 1];

  const float4* ap = (const float4*)(aggR + (size_t)n * EF + 8 * p);
  float4 a0 = ap[0], a1 = ap[1];
  float s8[8] = {a0.x, a0.y, a0.z, a0.w, a1.x, a1.y, a1.z, a1.w};

  float z[NF];
  if (p == 0) {
    const float4* hp = (const float4*)(hpart + (size_t)n * NF);
#pragma unroll
    for (int j4 = 0; j4 < 8; ++j4) {
      float4 v = hp[j4];
      z[4 * j4] = v.x; z[4 * j4 + 1] = v.y; z[4 * j4 + 2] = v.z; z[4 * j4 + 3] = v.w;
    }
  } else {
    float dg = (float)(o1 - o0);
#pragma unroll
    for (int j = 0; j < NF; ++j) z[j] = dg * sbvec[j];
  }
#pragma unroll
  for (int k = 0; k < 8; ++k) {
    float v = s8[k];
    const float4* wr = (const float4*)(sWnc + (8 * p + k) * NF);
#pragma unroll
    for (int j4 = 0; j4 < 8; ++j4) {
      float4 w = wr[j4];
      z[4 * j4 + 0] = fmaf(v, w.x, z[4 * j4 + 0]);
      z[4 * j4 + 1] = fmaf(v, w.y, z[4 * j4 + 1]);
      z[4 * j4 + 2] = fmaf(v, w.z, z[4 * j4 + 2]);
      z[4 * j4 + 3] = fmaf(v, w.w, z[4 * j4 + 3]);
    }
  }
#pragma unroll
  for (int j = 0; j < NF; ++j) z[j] += __shfl_xor(z[j], 1, 64);
#pragma unroll
  for (int j = 0; j < NF; ++j) z[j] = sigmoidf_(z[j]);

  float o[NC];
  float pm = (p == 0) ? 1.0f : 0.0f;
#pragma unroll
  for (int c = 0; c < NC; ++c) o[c] = pm * sBNF[c];
  for (int k = 0; k < 16; ++k) {
    float v = z[16 * p + k];
    const float* wr = sWNF + (16 * p + k) * NC;
#pragma unroll
    for (int c = 0; c < NC; ++c) o[c] = fmaf(v, wr[c], o[c]);
  }
#pragma unroll
  for (int c = 0; c < NC; ++c) o[c] += __shfl_xor(o[c], 1, 64);
  if (p == 0) {
    float4* op = (float4*)(out + (size_t)n * NC);
    op[0] = make_float4(o[0], o[1], o[2], o[3]);
    op[1] = make_float4(o[4], o[5], o[6], o[7]);
  }
}

// ---------------------------------------------------------------------------
extern "C" void kernel_launch(void* const* d_in, const int* in_sizes, int n_in,
                              void* d_out, int out_size, void* d_ws, size_t ws_size,
                              hipStream_t stream) {
  const float* node_feat = (const float*)d_in[0];
  const float* edge_feat = (const float*)d_in[1];
  const int*   src = (const int*)d_in[2];
  const int*   dst = (const int*)d_in[3];
  const float* Wn  = (const float*)d_in[4];
  const float* bn  = (const float*)d_in[5];
  const float* We  = (const float*)d_in[6];
  const float* be  = (const float*)d_in[7];
  const float* Wem = (const float*)d_in[8];
  const float* bem = (const float*)d_in[9];
  const float* Wnm = (const float*)d_in[10];
  const float* bnm = (const float*)d_in[11];
  const float* Wfc = (const float*)d_in[12];
  const float* bfc = (const float*)d_in[13];
  float* out = (float*)d_out;

  float* ws    = (float*)d_ws;
  float* e_b0  = ws;                                   // 3,840,000 f
  float* e_b1  = e_b0 + (size_t)N_EDGES * EF;          // 3,840,000 f
  float* hpart = e_b1 + (size_t)N_EDGES * EF;          //   960,000 f
  float* Ps0   = hpart + (size_t)N_NODES * NF;         //   480,000 f
  float* Pd0   = Ps0 + (size_t)N_NODES * EF;
  float* Ps1   = Pd0 + (size_t)N_NODES * EF;
  float* Pd1   = Ps1 + (size_t)N_NODES * EF;
  float* G0    = Pd1 + (size_t)N_NODES * EF;           //   480,000 f
  float* G1    = G0 + (size_t)N_NODES * EF;            //   480,000 f
  float* wbuf  = G1 + (size_t)N_NODES * EF;            //     4,096 f
  int* cnt     = (int*)(wbuf + 4096);                  //    30,000 i
  int* off     = cnt + N_NODES;                        //    30,001 i
  int* cursor  = off + N_NODES + 1;                    //    30,000 i
  unsigned short* src_s = (unsigned short*)(cursor + N_NODES);  // 240,000 u16
  unsigned short* dst_s = src_s + N_EDGES;                      // 240,000 u16
  float* PsA[2] = {Ps0, Ps1};
  float* PdA[2] = {Pd0, Pd1};
  float* EbA[2] = {e_b0, e_b1};
  float* GA[2]  = {G0, G1};

  // --- preamble: counting sort + weight folding; zero both agg buffers ---
  hipMemsetAsync(cnt, 0, (size_t)N_NODES * sizeof(int), stream);
  hipMemsetAsync(G0, 0, (size_t)2 * N_NODES * EF * sizeof(float), stream);
  hist_pre_kernel<<<EB_GRID + 1, 256, 0, stream>>>(
      dst, cnt, Wn, bn, We, be, Wem, bem, Wnm, bnm, Wfc, bfc, wbuf);
  scan_kernel<<<1, 1024, 0, stream>>>(cnt, off, cursor);
  scatter_init_kernel<<<EB_GRID + NB2_GRID, 256, 0, stream>>>(
      edge_feat, src, dst, cursor, src_s, dst_s, e_b0,
      node_feat, wbuf, Ps1, Pd1, hpart);
  // one-time gather: agg0 = segsum(initial sorted e rows) -> G0
  agg0_kernel<<<NB2_GRID, 256, 0, stream>>>(e_b0, off, G0);

  // 11 fused (node_i || edge_i) passes.
  // node_i reads GA[(i+1)&1] (then zeroes it); edge_i writes GA[i&1].
  // e double-buffer: both read EbA[(i+1)&1], edge writes EbA[i&1].
  // P ping-pong: edge_i reads P[i&1]; node_i writes P[(i+1)&1].
  for (int i = 1; i <= 11; ++i) {
    fused4_kernel<<<NB2_GRID + EB_GRID, 256, 0, stream>>>(
        EbA[(i + 1) & 1], EbA[i & 1], src_s, dst_s,
        PsA[i & 1], PdA[i & 1], hpart, off, wbuf,
        PsA[(i + 1) & 1], PdA[(i + 1) & 1],
        GA[(i + 1) & 1], GA[i & 1], (i < 11) ? 1 : 0);
  }
  // node pass 12 + output head; edge_11 wrote agg into GA[1].
  final_kernel<<<NB2_GRID, 256, 0, stream>>>(GA[1], hpart, off, wbuf, out);
}